// Round 17
// baseline (1377.550 us; speedup 1.0000x reference)
//
#include <hip/hip_runtime.h>
#include <math.h>

typedef unsigned short ushort_t;
typedef __attribute__((ext_vector_type(8))) short bf16x8;
typedef __attribute__((ext_vector_type(4))) float f32x4;

// ---------------- helpers ----------------
__device__ __forceinline__ float geluf(float x){
  return 0.5f*x*(1.0f+erff(x*0.70710678118654752440f));
}
__device__ __forceinline__ float bfu(unsigned int u){
  union { unsigned int i; float f; } v; v.i = (u & 0xffffu) << 16; return v.f;
}
__device__ __forceinline__ unsigned int f2b(float f){
  union { float f; unsigned int i; } v; v.f = f;
  unsigned int r = v.i + 0x7fffu + ((v.i >> 16) & 1u);
  return (r >> 16);
}

// Problem constants
// B=512, N=197, C=384, T=196 image tokens
// d_out layout (floats): out[512] | cosine[512] | query_class[512*384] | support_class[512*384]

// ---------------- A: fused mean + fc1 + LN-stats (one block per (s,b)) ----------------
// Streams the block's X tile (302 KB) from HBM ONCE: f32 column sums -> meanb
// (exact), bf16 copy -> LDS (151 KB). Then fc1 in-block (w1/w2 L2-resident),
// mlp1 written to global, and per-row (mu,rstd) computed from the LDS bf16 copy
// + f32 m1 — eliminating k_stats's whole 619 MB input re-read.
// bf16-x stats error: mu ~2e-4, rstd ~0.1% -> LN-output ~3e-4 (abs margin 12x).
__global__ __launch_bounds__(384) void k_ms(
    const float* __restrict__ x0, const float* __restrict__ x1,
    const float* __restrict__ x2, const float* __restrict__ x3,
    const float* __restrict__ w1, const float* __restrict__ b1,
    const float* __restrict__ w2, const float* __restrict__ b2,
    float* __restrict__ mlp1, float* __restrict__ mu, float* __restrict__ rstd){
  __shared__ ushort_t Xb[197][384];   // 151,296 B bf16 copy of the tile
  __shared__ float4 red[4][96];       // 6,144 B column-sum reduce
  __shared__ float ms[384];
  __shared__ float hs[96];
  __shared__ float m1s[384];
  int sb = blockIdx.x;
  int s = sb >> 9, b = sb & 511;
  const float* x = (s==0)?x0:(s==1)?x1:(s==2)?x2:x3;
  int tid = threadIdx.x;
  int c4 = tid % 96, g = tid / 96;    // 4 row-groups x 96 float4-slots
  const float* p = x + ((size_t)b*197)*384 + c4*4;
  float4 a0 = {0.f,0.f,0.f,0.f}, a1 = {0.f,0.f,0.f,0.f};
  int t = g;
  for (; t + 4 < 197; t += 8){
    float4 v0 = *reinterpret_cast<const float4*>(p + (size_t)t*384);
    float4 v1 = *reinterpret_cast<const float4*>(p + (size_t)(t+4)*384);
    uint2 pk0; pk0.x = f2b(v0.x) | (f2b(v0.y)<<16); pk0.y = f2b(v0.z) | (f2b(v0.w)<<16);
    uint2 pk1; pk1.x = f2b(v1.x) | (f2b(v1.y)<<16); pk1.y = f2b(v1.z) | (f2b(v1.w)<<16);
    *reinterpret_cast<uint2*>(&Xb[t][c4*4]) = pk0;
    *reinterpret_cast<uint2*>(&Xb[t+4][c4*4]) = pk1;
    a0.x += v0.x; a0.y += v0.y; a0.z += v0.z; a0.w += v0.w;
    a1.x += v1.x; a1.y += v1.y; a1.z += v1.z; a1.w += v1.w;
  }
  if (t < 197){
    float4 v = *reinterpret_cast<const float4*>(p + (size_t)t*384);
    uint2 pk; pk.x = f2b(v.x) | (f2b(v.y)<<16); pk.y = f2b(v.z) | (f2b(v.w)<<16);
    *reinterpret_cast<uint2*>(&Xb[t][c4*4]) = pk;
    a0.x += v.x; a0.y += v.y; a0.z += v.z; a0.w += v.w;
  }
  a0.x += a1.x; a0.y += a1.y; a0.z += a1.z; a0.w += a1.w;
  red[g][c4] = a0;
  __syncthreads();
  // column means (over 197 tokens) -> ms
  if (tid < 96){
    float4 a = red[0][tid], bb = red[1][tid], c = red[2][tid], d = red[3][tid];
    ms[tid*4+0] = (a.x+bb.x+c.x+d.x)*(1.0f/197.0f);
    ms[tid*4+1] = (a.y+bb.y+c.y+d.y)*(1.0f/197.0f);
    ms[tid*4+2] = (a.z+bb.z+c.z+d.z)*(1.0f/197.0f);
    ms[tid*4+3] = (a.w+bb.w+c.w+d.w)*(1.0f/197.0f);
  }
  __syncthreads();
  // fc1 hidden (384 -> 96, gelu)
  if (tid < 96){
    float a = b1[tid];
    for (int c = 0; c < 384; ++c) a += ms[c]*w1[c*96+tid];
    hs[tid] = geluf(a);
  }
  __syncthreads();
  // fc1 output (96 -> 384) -> m1s + global mlp1
  {
    float a = b2[tid];
    for (int j = 0; j < 96; ++j) a += hs[j]*w2[j*384+tid];
    m1s[tid] = a;
    mlp1[(size_t)sb*384 + tid] = a;
  }
  __syncthreads();
  // per-row LN stats from bf16 LDS copy: 24 groups of 16 lanes, 9 sweeps
  int grp = tid >> 4, il = tid & 15;
  for (int it = 0; it < 9; ++it){
    int tr = it*24 + grp;
    if (tr < 197){
      float sum = 0.f, sq = 0.f;
      #pragma unroll
      for (int e = 0; e < 6; ++e){
        int c = il*4 + e*64;
        uint2 v = *reinterpret_cast<const uint2*>(&Xb[tr][c]);
        float q0 = bfu(v.x)      + m1s[c+0];
        float q1 = bfu(v.x>>16)  + m1s[c+1];
        float q2 = bfu(v.y)      + m1s[c+2];
        float q3 = bfu(v.y>>16)  + m1s[c+3];
        sum += q0+q1+q2+q3;
        sq  += q0*q0+q1*q1+q2*q2+q3*q3;
      }
      #pragma unroll
      for (int o=1;o<16;o<<=1){ sum += __shfl_xor(sum,o); sq += __shfl_xor(sq,o); }
      if (il == 0){
        int row = sb*197 + tr;
        float m = sum*(1.0f/384.0f);
        mu[row] = m;
        rstd[row] = rsqrtf(sq*(1.0f/384.0f) - m*m + 1e-5f);
      }
    }
  }
}

// ---------------- D: class token rows -> d_out ----------------
__global__ __launch_bounds__(384) void k_class(
    const float* __restrict__ x0, const float* __restrict__ x1,
    const float* __restrict__ mlp1, const float* __restrict__ mu,
    const float* __restrict__ rstd, const float* __restrict__ g1,
    const float* __restrict__ bb1, float* __restrict__ dout){
  int s = blockIdx.x >> 9, b = blockIdx.x & 511, c = threadIdx.x;
  const float* x = s ? x1 : x0;
  int srow = (s*512 + b)*197;
  float v = x[((size_t)b*197)*384 + c] + mlp1[((size_t)s*512+b)*384 + c];
  float y = (v - mu[srow])*rstd[srow]*g1[c] + bb1[c];
  dout[1024 + (size_t)s*196608 + (size_t)b*384 + c] = y;
}

// ---------------- E: cosine head on class tokens ----------------
__global__ __launch_bounds__(384) void k_cosine(
    const float* __restrict__ w1, const float* __restrict__ b1,
    const float* __restrict__ w2, const float* __restrict__ b2,
    float* __restrict__ dout){
  __shared__ float qrow[384], srw[384], hq[96], hs[96];
  __shared__ float rd0[384], rd1[384], rd2[384];
  int b = blockIdx.x, tid = threadIdx.x;
  qrow[tid] = dout[1024   + (size_t)b*384 + tid];
  srw[tid]  = dout[197632 + (size_t)b*384 + tid];
  __syncthreads();
  if (tid < 96){
    float a = b1[tid];
    for (int c=0;c<384;++c) a += qrow[c]*w1[c*96+tid];
    hq[tid] = geluf(a);
  } else if (tid < 192){
    int j = tid - 96;
    float a = b1[j];
    for (int c=0;c<384;++c) a += srw[c]*w1[c*96+j];
    hs[j] = geluf(a);
  }
  __syncthreads();
  float qx = b2[tid], sy = b2[tid];
  for (int j=0;j<96;++j){ qx += hq[j]*w2[j*384+tid]; sy += hs[j]*w2[j*384+tid]; }
  rd0[tid] = qx*sy; rd1[tid] = qx*qx; rd2[tid] = sy*sy;
  __syncthreads();
  if (tid < 64){
    float d=0.f,nq=0.f,ns=0.f;
    for (int i=tid;i<384;i+=64){ d+=rd0[i]; nq+=rd1[i]; ns+=rd2[i]; }
    #pragma unroll
    for (int o=32;o;o>>=1){ d+=__shfl_down(d,o); nq+=__shfl_down(nq,o); ns+=__shfl_down(ns,o); }
    if (tid==0) dout[512 + b] = d / (fmaxf(sqrtf(nq),1e-8f)*fmaxf(sqrtf(ns),1e-8f));
  }
}

// ---------------- W: weight prep (bf16 transposes, zero-padded) ----------------
// grid 504, block 256 (504*256 = 129024).
__global__ __launch_bounds__(256) void k_wt(
    const float* __restrict__ w1_4, const float* __restrict__ w2_4,
    const float* __restrict__ w1_3, const float* __restrict__ w2_3,
    ushort_t* __restrict__ w1t, ushort_t* __restrict__ w2t,
    ushort_t* __restrict__ w1t3, ushort_t* __restrict__ w2t3){
  int idx = blockIdx.x*256 + threadIdx.x;
  if (idx < 36864){
    int c = idx / 96, j = idx - c*96;
    w2t[idx] = (ushort_t)f2b(w2_4[(size_t)j*384 + c]);
  } else if (idx < 73728){
    int k = idx - 36864;
    int j = k / 384, c = k - j*384;
    w1t[k] = (ushort_t)f2b(w1_4[(size_t)c*96 + j]);
  } else if (idx < 102400){
    int k = idx - 73728;
    int j = k / 224, t = k - j*224;
    w1t3[k] = (t < 196) ? (ushort_t)f2b(w1_3[(size_t)t*128 + j]) : (ushort_t)0;
  } else {
    int k = idx - 102400;
    int tp = k / 128, j = k - tp*128;
    w2t3[k] = (tp < 196) ? (ushort_t)f2b(w2_3[(size_t)j*196 + tp]) : (ushort_t)0;
  }
}

// ---------------- F: fc3 fused MFMA (one s-half per launch) ----------------
// grid 512*6 (b, c-tile of 64), block 256 = 4 waves; wave = 16 c rows.
__global__ __launch_bounds__(256) void k_fc3(
    const float* __restrict__ x,         // fqs or fss
    const float* __restrict__ m1_base,   // mlp1 + s*512*384
    const float* __restrict__ mu_s,      // mu + s*100864
    const float* __restrict__ rstd_s,
    const float* __restrict__ g1, const float* __restrict__ bln1,
    const ushort_t* __restrict__ w1t3,   // [128][224] bf16
    const float* __restrict__ b1,        // fc3_b1 [128]
    const ushort_t* __restrict__ w2t3,   // [208][128] bf16
    const float* __restrict__ b2, const float* __restrict__ g3,
    const float* __restrict__ b3,
    ushort_t* __restrict__ Qout){        // Qb or Sb
  __shared__ ushort_t Xs[64][232];       // X^T tile; Hs overlays cols [0,128) per wave
  __shared__ ushort_t W2s[112][136];     // w2t3 half (17x16B stride: bank-safe)
  __shared__ float m1s[64], g1s[64], b1s[64];
  __shared__ float mus[196], rss[196];
  __shared__ float b1j[128];
  __shared__ float b2s[208], g3s[208], b3s[208];
  int bid = blockIdx.x;
  int b = bid/6, c0 = (bid%6)*64;
  int tid = threadIdx.x;
  // stage coefficients
  if (tid < 64){
    m1s[tid] = m1_base[(size_t)b*384 + c0 + tid];
    g1s[tid] = g1[c0+tid]; b1s[tid] = bln1[c0+tid];
  }
  if (tid < 128) b1j[tid] = b1[tid];
  if (tid < 196){ mus[tid] = mu_s[b*197 + tid + 1]; rss[tid] = rstd_s[b*197 + tid + 1]; }
  if (tid < 208){
    float bb=0.f, gg=0.f, b3v=0.f;
    if (tid < 196){ bb = b2[tid]; gg = g3[tid]; b3v = b3[tid]; }
    b2s[tid]=bb; g3s[tid]=gg; b3s[tid]=b3v;
  }
  // stage W2s part 1 (w2t3 rows 0..111)
  for (int i = tid; i < 112*16; i += 256){
    int r = i >> 4, q = i & 15;
    *reinterpret_cast<uint4*>(&W2s[r][q*8]) =
        *reinterpret_cast<const uint4*>(&w2t3[(size_t)r*128 + q*8]);
  }
  // zero the t-pad of Xs ([196,224) as uints; [224,232) never read)
  for (int i = tid; i < 64*14; i += 256){
    *reinterpret_cast<unsigned int*>(&Xs[i/14][196 + 2*(i%14)]) = 0u;
  }
  __syncthreads();
  // phase 1: stage LN'd X^T tile by t-pairs (98 tpairs x 16 c4-slots = 1568)
  for (int e = 0; e < 7; ++e){
    int idx = e*256 + tid;
    if (idx < 1568){
      int t2 = idx >> 4, c4 = idx & 15;
      int t0 = t2*2;
      const float* xr = &x[((size_t)b*197 + t0 + 1)*384 + c0 + c4*4];
      float4 xv0 = *reinterpret_cast<const float4*>(xr);
      float4 xv1 = *reinterpret_cast<const float4*>(xr + 384);
      float mu0 = mus[t0], rs0 = rss[t0], mu1 = mus[t0+1], rs1 = rss[t0+1];
      int c = c4*4;
      unsigned int u0 = f2b(((xv0.x + m1s[c+0]) - mu0)*rs0*g1s[c+0] + b1s[c+0])
                      | (f2b(((xv1.x + m1s[c+0]) - mu1)*rs1*g1s[c+0] + b1s[c+0]) << 16);
      unsigned int u1 = f2b(((xv0.y + m1s[c+1]) - mu0)*rs0*g1s[c+1] + b1s[c+1])
                      | (f2b(((xv1.y + m1s[c+1]) - mu1)*rs1*g1s[c+1] + b1s[c+1]) << 16);
      unsigned int u2 = f2b(((xv0.z + m1s[c+2]) - mu0)*rs0*g1s[c+2] + b1s[c+2])
                      | (f2b(((xv1.z + m1s[c+2]) - mu1)*rs1*g1s[c+2] + b1s[c+2]) << 16);
      unsigned int u3 = f2b(((xv0.w + m1s[c+3]) - mu0)*rs0*g1s[c+3] + b1s[c+3])
                      | (f2b(((xv1.w + m1s[c+3]) - mu1)*rs1*g1s[c+3] + b1s[c+3]) << 16);
      *reinterpret_cast<unsigned int*>(&Xs[c+0][t0]) = u0;
      *reinterpret_cast<unsigned int*>(&Xs[c+1][t0]) = u1;
      *reinterpret_cast<unsigned int*>(&Xs[c+2][t0]) = u2;
      *reinterpret_cast<unsigned int*>(&Xs[c+3][t0]) = u3;
    }
  }
  __syncthreads();
  int w = tid >> 6, lane = tid & 63;
  int cl = lane & 15, kg = lane >> 4;
  // GEMM1: h = gelu(Xt @ w1 + b1); A register double-buffered
  f32x4 hacc[8];
  #pragma unroll
  for (int jf=0;jf<8;++jf){ f32x4 z={0.f,0.f,0.f,0.f}; hacc[jf]=z; }
  const ushort_t* zrow = &Xs[w*16 + cl][kg*8];
  const ushort_t* abase = w1t3 + (size_t)cl*224 + kg*8;
  bf16x8 aC[8], aN[8];
  #pragma unroll
  for (int jf=0;jf<8;++jf)
    aC[jf] = *reinterpret_cast<const bf16x8*>(abase + jf*16*224);
  for (int kc = 0; kc < 7; ++kc){
    bf16x8 xb = *reinterpret_cast<const bf16x8*>(zrow + kc*32);
    if (kc < 6){
      #pragma unroll
      for (int jf=0;jf<8;++jf)
        aN[jf] = *reinterpret_cast<const bf16x8*>(abase + jf*16*224 + (kc+1)*32);
    }
    #pragma unroll
    for (int jf=0;jf<8;++jf)
      hacc[jf] = __builtin_amdgcn_mfma_f32_16x16x32_bf16(aC[jf], xb, hacc[jf], 0, 0, 0);
    #pragma unroll
    for (int jf=0;jf<8;++jf) aC[jf] = aN[jf];
  }
  // D: row = j = jf*16+kg*4+r, col = c = cl -> overlay into the wave's OWN Xs rows.
  #pragma unroll
  for (int jf=0;jf<8;++jf){
    f32x4 y = hacc[jf];
    int j0 = jf*16 + kg*4;
    uint2 pk;
    pk.x = f2b(geluf(y[0]+b1j[j0+0])) | (f2b(geluf(y[1]+b1j[j0+1]))<<16);
    pk.y = f2b(geluf(y[2]+b1j[j0+2])) | (f2b(geluf(y[3]+b1j[j0+3]))<<16);
    *reinterpret_cast<uint2*>(&Xs[w*16 + cl][j0]) = pk;
  }
  // GEMM2: y = h @ w2 (+b2 in epilogue); B from LDS in two halves
  f32x4 yacc[13];
  #pragma unroll
  for (int tf=0;tf<13;++tf){ f32x4 z={0.f,0.f,0.f,0.f}; yacc[tf]=z; }
  const ushort_t* hrow = &Xs[w*16 + cl][kg*8];
  // part A: tf 0..6 (t' rows 0..111 in W2s)
  for (int kc = 0; kc < 4; ++kc){
    bf16x8 hb = *reinterpret_cast<const bf16x8*>(hrow + kc*32);
    #pragma unroll
    for (int tf=0;tf<7;++tf){
      const ushort_t* bp = &W2s[tf*16 + cl][kg*8 + kc*32];
      yacc[tf] = __builtin_amdgcn_mfma_f32_16x16x32_bf16(
          hb, *reinterpret_cast<const bf16x8*>(bp), yacc[tf], 0, 0, 0);
    }
  }
  __syncthreads();
  // restage W2s with w2t3 rows 112..207 (96 rows)
  for (int i = tid; i < 96*16; i += 256){
    int r = i >> 4, q = i & 15;
    *reinterpret_cast<uint4*>(&W2s[r][q*8]) =
        *reinterpret_cast<const uint4*>(&w2t3[(size_t)(112 + r)*128 + q*8]);
  }
  __syncthreads();
  // part B: tf 7..12 (t' rows 112..207 -> W2s rows tf*16+cl-112)
  for (int kc = 0; kc < 4; ++kc){
    bf16x8 hb = *reinterpret_cast<const bf16x8*>(hrow + kc*32);
    #pragma unroll
    for (int tf=7;tf<13;++tf){
      const ushort_t* bp = &W2s[tf*16 + cl - 112][kg*8 + kc*32];
      yacc[tf] = __builtin_amdgcn_mfma_f32_16x16x32_bf16(
          hb, *reinterpret_cast<const bf16x8*>(bp), yacc[tf], 0, 0, 0);
    }
  }
  // epilogue: lane holds c = c0 + w*16 + kg*4 + r (r=0..3), t' = tf*16 + cl.
  float sum0=0.f,sum1=0.f,sum2=0.f,sum3=0.f, sq0=0.f,sq1=0.f,sq2=0.f,sq3=0.f;
  #pragma unroll
  for (int tf=0;tf<13;++tf){
    int tp = tf*16 + cl;
    float bb = b2s[tp];
    f32x4 y = yacc[tf];
    y[0]+=bb; y[1]+=bb; y[2]+=bb; y[3]+=bb;
    yacc[tf] = y;
    sum0+=y[0]; sum1+=y[1]; sum2+=y[2]; sum3+=y[3];
    sq0+=y[0]*y[0]; sq1+=y[1]*y[1]; sq2+=y[2]*y[2]; sq3+=y[3]*y[3];
  }
  #pragma unroll
  for (int o=1;o<16;o<<=1){
    sum0+=__shfl_xor(sum0,o); sum1+=__shfl_xor(sum1,o);
    sum2+=__shfl_xor(sum2,o); sum3+=__shfl_xor(sum3,o);
    sq0+=__shfl_xor(sq0,o); sq1+=__shfl_xor(sq1,o);
    sq2+=__shfl_xor(sq2,o); sq3+=__shfl_xor(sq3,o);
  }
  float m0=sum0*(1.0f/196.0f), m1v=sum1*(1.0f/196.0f), m2=sum2*(1.0f/196.0f), m3=sum3*(1.0f/196.0f);
  float r0=rsqrtf(sq0*(1.0f/196.0f)-m0*m0+1e-5f);
  float r1=rsqrtf(sq1*(1.0f/196.0f)-m1v*m1v+1e-5f);
  float r2=rsqrtf(sq2*(1.0f/196.0f)-m2*m2+1e-5f);
  float r3=rsqrtf(sq3*(1.0f/196.0f)-m3*m3+1e-5f);
  int cbase = c0 + w*16 + kg*4;
  #pragma unroll
  for (int tf=0;tf<13;++tf){
    int tp = tf*16 + cl;
    if (tp < 196){
      float gg = g3s[tp], bb3 = b3s[tp];
      f32x4 y = yacc[tf];
      unsigned int o0 = f2b((y[0]-m0)*r0*gg + bb3);
      unsigned int o1 = f2b((y[1]-m1v)*r1*gg + bb3);
      unsigned int o2 = f2b((y[2]-m2)*r2*gg + bb3);
      unsigned int o3 = f2b((y[3]-m3)*r3*gg + bb3);
      uint2 pk; pk.x = o0 | (o1<<16); pk.y = o2 | (o3<<16);
      *reinterpret_cast<uint2*>(&Qout[((size_t)b*196 + tp)*384 + cbase]) = pk;
    }
  }
}

// ---------------- H1: fc4 stage A (MFMA; one s-half per launch) ----------------
// grid 512*4 (b, t-tile of 64), block 256 = 4 waves; wave = 16 t x 96 j.
__global__ __launch_bounds__(256) void k_fc4a(
    const float* __restrict__ x,         // fq or fs
    const float* __restrict__ m1_base,   // mlp1 + s*512*384
    const float* __restrict__ mu_s,      // mu + s*100864
    const float* __restrict__ rstd_s,    // rstd + s*100864
    const float* __restrict__ g1, const float* __restrict__ bln1,
    const ushort_t* __restrict__ Qin,    // Qb or Sb
    const ushort_t* __restrict__ w1t,    // [96][384] bf16
    const float* __restrict__ b1mlp,
    ushort_t* __restrict__ h4s){         // h4 + s*512*196*96
  __shared__ ushort_t Zs[64][392];       // bf16 Z tile, padded stride
  __shared__ float m1s[384], g1s[384], b1s[384];
  __shared__ float mus[64], rss[64];
  __shared__ float b1m[96];
  int bid = blockIdx.x;
  int b = bid >> 2, tt0 = (bid & 3)*64;
  int tid = threadIdx.x;
  const float* m1 = m1_base + (size_t)b*384;
  for (int i = tid; i < 384; i += 256){ m1s[i] = m1[i]; g1s[i] = g1[i]; b1s[i] = bln1[i]; }
  if (tid < 96) b1m[tid] = b1mlp[tid];
  if (tid < 64){
    int t = tt0 + tid; int tc = t < 196 ? t : 195;
    mus[tid] = mu_s[b*197 + tc + 1]; rss[tid] = rstd_s[b*197 + tc + 1];
  }
  __syncthreads();
  // phase 1: Z build, 64 rows x 96 col4-slots = 6144 slots, 24 per thread
  for (int e = 0; e < 24; ++e){
    int v = e*256 + tid;
    int row = v/96, col4 = v - row*96;
    int t = tt0 + row; int tc = t < 196 ? t : 195;
    float valid = (t < 196) ? 1.f : 0.f;
    float4 xv = *reinterpret_cast<const float4*>(&x[((size_t)b*197 + tc + 1)*384 + col4*4]);
    uint2 qv = *reinterpret_cast<const uint2*>(&Qin[((size_t)b*196 + tc)*384 + col4*4]);
    float muv = mus[row], rsv = rss[row];
    int c = col4*4;
    float z0 = (((xv.x + m1s[c+0]) - muv)*rsv*g1s[c+0] + b1s[c+0]) * bfu(qv.x)      * valid;
    float z1 = (((xv.y + m1s[c+1]) - muv)*rsv*g1s[c+1] + b1s[c+1]) * bfu(qv.x>>16)  * valid;
    float z2 = (((xv.z + m1s[c+2]) - muv)*rsv*g1s[c+2] + b1s[c+2]) * bfu(qv.y)      * valid;
    float z3 = (((xv.w + m1s[c+3]) - muv)*rsv*g1s[c+3] + b1s[c+3]) * bfu(qv.y>>16)  * valid;
    uint2 pk; pk.x = f2b(z0) | (f2b(z1)<<16); pk.y = f2b(z2) | (f2b(z3)<<16);
    *reinterpret_cast<uint2*>(&Zs[row][col4*4]) = pk;
  }
  __syncthreads();
  // phase 2: MFMA GEMM1 (16t x 96j per wave, K=384)
  int w = tid >> 6, lane = tid & 63;
  int tr = tt0 + w*16 + (lane & 15);
  int kg = lane >> 4;
  f32x4 acc0 = {0.f,0.f,0.f,0.f}, acc1 = {0.f,0.f,0.f,0.f}, acc2 = {0.f,0.f,0.f,0.f};
  f32x4 acc3 = {0.f,0.f,0.f,0.f}, acc4 = {0.f,0.f,0.f,0.f}, acc5 = {0.f,0.f,0.f,0.f};
  const ushort_t* arow = w1t + (size_t)(lane & 15)*384 + kg*8;
  const ushort_t* zrow = &Zs[w*16 + (lane & 15)][kg*8];
  for (int kc = 0; kc < 12; ++kc){
    bf16x8 zb = *reinterpret_cast<const bf16x8*>(zrow + kc*32);
    bf16x8 a0 = *reinterpret_cast<const bf16x8*>(arow + kc*32);
    bf16x8 a1 = *reinterpret_cast<const bf16x8*>(arow + kc*32 + 16*384);
    bf16x8 a2 = *reinterpret_cast<const bf16x8*>(arow + kc*32 + 32*384);
    bf16x8 a3 = *reinterpret_cast<const bf16x8*>(arow + kc*32 + 48*384);
    bf16x8 a4 = *reinterpret_cast<const bf16x8*>(arow + kc*32 + 64*384);
    bf16x8 a5 = *reinterpret_cast<const bf16x8*>(arow + kc*32 + 80*384);
    acc0 = __builtin_amdgcn_mfma_f32_16x16x32_bf16(a0, zb, acc0, 0, 0, 0);
    acc1 = __builtin_amdgcn_mfma_f32_16x16x32_bf16(a1, zb, acc1, 0, 0, 0);
    acc2 = __builtin_amdgcn_mfma_f32_16x16x32_bf16(a2, zb, acc2, 0, 0, 0);
    acc3 = __builtin_amdgcn_mfma_f32_16x16x32_bf16(a3, zb, acc3, 0, 0, 0);
    acc4 = __builtin_amdgcn_mfma_f32_16x16x32_bf16(a4, zb, acc4, 0, 0, 0);
    acc5 = __builtin_amdgcn_mfma_f32_16x16x32_bf16(a5, zb, acc5, 0, 0, 0);
  }
  // epilogue: lane holds j = jb*16 + kg*4 + r (D row), t = tr (D col)
  if (tr < 196){
    ushort_t* dst = h4s + ((size_t)b*196 + tr)*96 + kg*4;
    #pragma unroll
    for (int jb = 0; jb < 6; ++jb){
      f32x4 y = (jb==0)?acc0:(jb==1)?acc1:(jb==2)?acc2:(jb==3)?acc3:(jb==4)?acc4:acc5;
      int j0 = jb*16 + kg*4;
      uint2 pk;
      pk.x = f2b(geluf(y[0]+b1m[j0+0])) | (f2b(geluf(y[1]+b1m[j0+1]))<<16);
      pk.y = f2b(geluf(y[2]+b1m[j0+2])) | (f2b(geluf(y[3]+b1m[j0+3]))<<16);
      *reinterpret_cast<uint2*>(dst + jb*16) = pk;
    }
  }
}

// ---------------- H2: fc4 stage B (MFMA; one s-half per launch) ----------------
// grid 512*4 (b, t-tile of 64), block 256 = 4 waves; wave = 16 t x 384 c.
__global__ __launch_bounds__(256) void k_fc4b(
    const ushort_t* __restrict__ h4s,    // h4 + s*512*196*96
    const ushort_t* __restrict__ w2t,    // [384][96] bf16
    const float* __restrict__ b2, const float* __restrict__ g4,
    const float* __restrict__ bb4,
    const float* __restrict__ cls_base,  // dout + 1024 + s*196608
    ushort_t* __restrict__ Qo){          // Qb or Sb
  __shared__ float b2s[384], g4s[384], b4s[384], cl_s[384];
  int bid = blockIdx.x;
  int b = bid >> 2, ttile = bid & 3;
  int tid = threadIdx.x, w = tid >> 6, lane = tid & 63;
  const float* cls = cls_base + (size_t)b*384;
  for (int i = tid; i < 384; i += 256){
    b2s[i] = b2[i]; g4s[i] = g4[i]; b4s[i] = bb4[i]; cl_s[i] = cls[i];
  }
  __syncthreads();
  int tr = ttile*64 + w*16 + (lane & 15);
  int trc = tr < 196 ? tr : 195;
  int kg = lane >> 4;
  const ushort_t* hp = h4s + ((size_t)b*196 + trc)*96 + kg*8;
  bf16x8 hb0 = *reinterpret_cast<const bf16x8*>(hp);
  bf16x8 hb1 = *reinterpret_cast<const bf16x8*>(hp + 32);
  bf16x8 hb2 = *reinterpret_cast<const bf16x8*>(hp + 64);
  const ushort_t* ap_base = w2t + (size_t)(lane & 15)*96 + kg*8;
  f32x4 acc[24];
  #pragma unroll
  for (int af = 0; af < 24; ++af){
    const ushort_t* ap = ap_base + (size_t)af*16*96;
    bf16x8 a0 = *reinterpret_cast<const bf16x8*>(ap);
    bf16x8 a1 = *reinterpret_cast<const bf16x8*>(ap + 32);
    bf16x8 a2 = *reinterpret_cast<const bf16x8*>(ap + 64);
    f32x4 z = {0.f,0.f,0.f,0.f};
    z = __builtin_amdgcn_mfma_f32_16x16x32_bf16(a0, hb0, z, 0, 0, 0);
    z = __builtin_amdgcn_mfma_f32_16x16x32_bf16(a1, hb1, z, 0, 0, 0);
    z = __builtin_amdgcn_mfma_f32_16x16x32_bf16(a2, hb2, z, 0, 0, 0);
    acc[af] = z;
  }
  // epilogue: lane holds c = af*16 + kg*4 + r  (r=0..3), t = tr (col)
  float sum = 0.f, sq = 0.f;
  #pragma unroll
  for (int af = 0; af < 24; ++af){
    int cb = af*16 + kg*4;
    float4 bv = *reinterpret_cast<const float4*>(&b2s[cb]);
    f32x4 y = acc[af];
    y[0] += bv.x; y[1] += bv.y; y[2] += bv.z; y[3] += bv.w;
    acc[af] = y;
    sum += y[0]+y[1]+y[2]+y[3];
    sq  += y[0]*y[0]+y[1]*y[1]+y[2]*y[2]+y[3]*y[3];
  }
  sum += __shfl_xor(sum, 16); sum += __shfl_xor(sum, 32);
  sq  += __shfl_xor(sq, 16);  sq  += __shfl_xor(sq, 32);
  float m4 = sum*(1.0f/384.0f);
  float rs = rsqrtf(sq*(1.0f/384.0f) - m4*m4 + 1e-5f);
  float s2 = 0.f;
  #pragma unroll
  for (int af = 0; af < 24; ++af){
    int cb = af*16 + kg*4;
    float4 gv = *reinterpret_cast<const float4*>(&g4s[cb]);
    float4 bb = *reinterpret_cast<const float4*>(&b4s[cb]);
    float4 cv = *reinterpret_cast<const float4*>(&cl_s[cb]);
    f32x4 y = acc[af];
    y[0] = (y[0]-m4)*rs*gv.x + bb.x + 0.5f*cv.x;
    y[1] = (y[1]-m4)*rs*gv.y + bb.y + 0.5f*cv.y;
    y[2] = (y[2]-m4)*rs*gv.z + bb.z + 0.5f*cv.z;
    y[3] = (y[3]-m4)*rs*gv.w + bb.w + 0.5f*cv.w;
    acc[af] = y;
    s2 += y[0]*y[0]+y[1]*y[1]+y[2]*y[2]+y[3]*y[3];
  }
  s2 += __shfl_xor(s2, 16); s2 += __shfl_xor(s2, 32);
  float inv = 1.0f/fmaxf(sqrtf(s2), 1e-12f);
  float sm = 0.f;
  #pragma unroll
  for (int af = 0; af < 24; ++af){
    f32x4 y = acc[af];
    y[0]*=inv; y[1]*=inv; y[2]*=inv; y[3]*=inv;
    acc[af] = y;
    sm += y[0]+y[1]+y[2]+y[3];
  }
  sm += __shfl_xor(sm, 16); sm += __shfl_xor(sm, 32);
  sm *= (1.0f/384.0f);
  if (tr < 196){
    ushort_t* dst = Qo + ((size_t)b*196 + tr)*384 + kg*4;
    #pragma unroll
    for (int af = 0; af < 24; ++af){
      f32x4 y = acc[af];
      uint2 pk;
      pk.x = f2b(y[0]-sm) | (f2b(y[1]-sm)<<16);
      pk.y = f2b(y[2]-sm) | (f2b(y[3]-sm)<<16);
      *reinterpret_cast<uint2*>(dst + af*16) = pk;
    }
  }
}

// ---------------- I: batched einsum + fused 2x2 pooling (MFMA) ----------------
// grid 512*16 (b, qt, st), block 256 = 4 waves; wave = 32x32 output tile.
// XCD-chunked bijective swizzle + register double-buffered fragments.
__global__ __launch_bounds__(256) void k_sim(
    const ushort_t* __restrict__ Q, const ushort_t* __restrict__ S,
    float* __restrict__ P){
  int bid0 = blockIdx.x;
  int bx = (bid0 & 7)*1024 + (bid0 >> 3);   // bijective: consecutive work-b per XCD
  int b = bx >> 4, qt = (bx >> 2) & 3, st = bx & 3;
  int tid = threadIdx.x;
  int w = tid >> 6, lane = tid & 63;
  int wr = w >> 1, wc = w & 1;
  int q0 = qt*64 + wr*32, s0 = st*64 + wc*32;
  int rrow = lane & 15, kg = lane >> 4;
  const ushort_t* Qb_ = Q + (size_t)b*196*384;
  const ushort_t* Sb_ = S + (size_t)b*196*384;
  int qr0 = min(q0 + rrow, 195), qr1 = min(q0 + 16 + rrow, 195);
  int sr0 = min(s0 + rrow, 195), sr1 = min(s0 + 16 + rrow, 195);
  const ushort_t* qp0 = Qb_ + (size_t)qr0*384 + kg*8;
  const ushort_t* qp1 = Qb_ + (size_t)qr1*384 + kg*8;
  const ushort_t* sp0 = Sb_ + (size_t)sr0*384 + kg*8;
  const ushort_t* sp1 = Sb_ + (size_t)sr1*384 + kg*8;
  f32x4 acc00 = {0.f,0.f,0.f,0.f}, acc01 = {0.f,0.f,0.f,0.f};
  f32x4 acc10 = {0.f,0.f,0.f,0.f}, acc11 = {0.f,0.f,0.f,0.f};
  bf16x8 qa0 = *reinterpret_cast<const bf16x8*>(qp0);
  bf16x8 qa1 = *reinterpret_cast<const bf16x8*>(qp1);
  bf16x8 sa0 = *reinterpret_cast<const bf16x8*>(sp0);
  bf16x8 sa1 = *reinterpret_cast<const bf16x8*>(sp1);
  for (int kc = 0; kc < 11; ++kc){
    int koff = (kc+1)*32;
    bf16x8 nq0 = *reinterpret_cast<const bf16x8*>(qp0 + koff);
    bf16x8 nq1 = *reinterpret_cast<const bf16x8*>(qp1 + koff);
    bf16x8 ns0 = *reinterpret_cast<const bf16x8*>(sp0 + koff);
    bf16x8 ns1 = *reinterpret_cast<const bf16x8*>(sp1 + koff);
    acc00 = __builtin_amdgcn_mfma_f32_16x16x32_bf16(qa0, sa0, acc00, 0, 0, 0);
    acc01 = __builtin_amdgcn_mfma_f32_16x16x32_bf16(qa0, sa1, acc01, 0, 0, 0);
    acc10 = __builtin_amdgcn_mfma_f32_16x16x32_bf16(qa1, sa0, acc10, 0, 0, 0);
    acc11 = __builtin_amdgcn_mfma_f32_16x16x32_bf16(qa1, sa1, acc11, 0, 0, 0);
    qa0 = nq0; qa1 = nq1; sa0 = ns0; sa1 = ns1;
  }
  acc00 = __builtin_amdgcn_mfma_f32_16x16x32_bf16(qa0, sa0, acc00, 0, 0, 0);
  acc01 = __builtin_amdgcn_mfma_f32_16x16x32_bf16(qa0, sa1, acc01, 0, 0, 0);
  acc10 = __builtin_amdgcn_mfma_f32_16x16x32_bf16(qa1, sa0, acc10, 0, 0, 0);
  acc11 = __builtin_amdgcn_mfma_f32_16x16x32_bf16(qa1, sa1, acc11, 0, 0, 0);
  int c = lane & 15, g = lane >> 4;
  float* Pb = P + (size_t)b*98*98;
  #pragma unroll
  for (int i = 0; i < 2; ++i){
    #pragma unroll
    for (int j = 0; j < 2; ++j){
      f32x4 v = (i==0) ? (j==0 ? acc00 : acc01) : (j==0 ? acc10 : acc11);
      float p0 = v[0] + v[1];   // rows 4g, 4g+1
      float p1 = v[2] + v[3];   // rows 4g+2, 4g+3
      float t0 = p0 + __shfl_xor(p0, 1);
      float t1 = p1 + __shfl_xor(p1, 1);
      if (!(c & 1)){
        int qp = (q0 + 16*i + 4*g) >> 1;
        int sp = (s0 + 16*j + c) >> 1;
        if (sp < 98){
          if (qp     < 98) Pb[(size_t)(qp    )*98 + sp] = 0.25f*t0;
          if (qp + 1 < 98) Pb[(size_t)(qp + 1)*98 + sp] = 0.25f*t1;
        }
      }
    }
  }
}

// ---------------- J1: fc2 split-K GEMM  Cpart[ks] = P2-chunk @ w1-chunk ----------------
// grid 64*14 (m-block of 8 rows, k-split of 686), block 256 (= N columns)
__global__ __launch_bounds__(256) void k_fc2a(
    const float* __restrict__ P, const float* __restrict__ w1,
    float* __restrict__ Cpart){
  __shared__ float p2[8][688];
  int bx = blockIdx.x;
  int mb = bx & 63, ks = bx >> 6;      // 14 k-splits of 686 (14*686 = 9604)
  int b0 = mb*8, k0 = ks*686;
  int tid = threadIdx.x;
  for (int idx = tid; idx < 8*686; idx += 256){
    int r = idx / 686, i = idx - r*686;
    float v = P[(size_t)(b0+r)*9604 + k0 + i];
    p2[r][i] = v*v;
  }
  __syncthreads();
  float acc[8];
  #pragma unroll
  for (int r=0;r<8;++r) acc[r]=0.f;
  for (int ii=0; ii<686; ++ii){
    float w = w1[(size_t)(k0+ii)*256 + tid];
    #pragma unroll
    for (int r=0;r<8;++r) acc[r] += p2[r][ii]*w;
  }
  #pragma unroll
  for (int r=0;r<8;++r) Cpart[((size_t)ks*512 + b0 + r)*256 + tid] = acc[r];
}

// ---------------- J2: fc2 reduce + gelu + w2 dot ----------------
// grid 512 (one b each), block 256
__global__ __launch_bounds__(256) void k_fc2b(
    const float* __restrict__ Cpart, const float* __restrict__ b1,
    const float* __restrict__ w2, const float* __restrict__ b2,
    float* __restrict__ outp){
  __shared__ float red[4];
  int b = blockIdx.x, tid = threadIdx.x;
  float s = 0.f;
  for (int ks = 0; ks < 14; ++ks) s += Cpart[((size_t)ks*512 + b)*256 + tid];
  float h = geluf(s + b1[tid]) * w2[tid];
  #pragma unroll
  for (int o=32;o;o>>=1) h += __shfl_down(h,o);
  int w = tid >> 6, lane = tid & 63;
  if (lane==0) red[w] = h;
  __syncthreads();
  if (tid==0) outp[b] = red[0]+red[1]+red[2]+red[3] + b2[0];
}

// ---------------- launch ----------------
extern "C" void kernel_launch(void* const* d_in, const int* in_sizes, int n_in,
                              void* d_out, int out_size, void* d_ws, size_t ws_size,
                              hipStream_t stream){
  const float* fq  = (const float*)d_in[0];
  const float* fs  = (const float*)d_in[1];
  const float* fqs = (const float*)d_in[2];
  const float* fss = (const float*)d_in[3];
  const float* fc1_w1 = (const float*)d_in[4];
  const float* fc1_b1 = (const float*)d_in[5];
  const float* fc1_w2 = (const float*)d_in[6];
  const float* fc1_b2 = (const float*)d_in[7];
  const float* ln1_g = (const float*)d_in[8];
  const float* ln1_b = (const float*)d_in[9];
  const float* fc3_w1 = (const float*)d_in[10];
  const float* fc3_b1 = (const float*)d_in[11];
  const float* fc3_w2 = (const float*)d_in[12];
  const float* fc3_b2 = (const float*)d_in[13];
  const float* ln3_g = (const float*)d_in[14];
  const float* ln3_b = (const float*)d_in[15];
  const float* fc4_w1 = (const float*)d_in[16];
  const float* fc4_b1 = (const float*)d_in[17];
  const float* fc4_w2 = (const float*)d_in[18];
  const float* fc4_b2 = (const float*)d_in[19];
  const float* ln4_g = (const float*)d_in[20];
  const float* ln4_b = (const float*)d_in[21];
  const float* fc2_w1 = (const float*)d_in[22];
  const float* fc2_b1 = (const float*)d_in[23];
  const float* fc2_w2 = (const float*)d_in[24];
  const float* fc2_b2 = (const float*)d_in[25];
  const float* cs_w1 = (const float*)d_in[26];
  const float* cs_b1 = (const float*)d_in[27];
  const float* cs_w2 = (const float*)d_in[28];
  const float* cs_b2 = (const float*)d_in[29];
  float* out = (float*)d_out;
  char* ws = (char*)d_ws;
  // ws layout (bytes):
  //   w2t  bf16 @0          (73,728)      [fc4 w2^T]
  //   w1t  bf16 @73728      (73,728)      [fc4 w1^T]
  //   w1t3 bf16 @147456     (57,344)      [fc3 w1^T, t-pad 224]
  //   w2t3 bf16 @204800     (53,248)      [fc3 w2^T, t'-pad 208]
  //   (meanb eliminated: mean+fc1+stats fused into k_ms)
  //   mlp1  f32 @3145728    (3,145,728)
  //   mu    f32 @6291456    (1,613,824)
  //   rstd  f32 @7905280    (1,613,824)
  //   h4    bf16 @9519104   (38,535,168)  [then P f32 + Cpart overlay]
  //   P     f32 @9519104    (19,668,992)  [overlays h4 (dead after fc4b)]
  //   Cpart f32 @29188096   (7,340,032)
  //   Qb    bf16 @59850752  (77,070,336)
  //   Sb    bf16 @136921088 (77,070,336)
  //   total 213,991,424 B
  ushort_t* w2t  = (ushort_t*)(ws + 0);
  ushort_t* w1t  = (ushort_t*)(ws + 73728);
  ushort_t* w1t3 = (ushort_t*)(ws + 147456);
  ushort_t* w2t3 = (ushort_t*)(ws + 204800);
  float* mlp1   = (float*)(ws + 3145728);
  float* mu     = (float*)(ws + 6291456);
  float* rstd   = (float*)(ws + 7905280);
  ushort_t* h4  = (ushort_t*)(ws + 9519104);
  float* P      = (float*)(ws + 9519104);     // overlays h4 (dead after fc4b)
  float* Cpart  = (float*)(ws + 29188096);    // after P, before Qb
  ushort_t* Qb  = (ushort_t*)(ws + 59850752);
  ushort_t* Sb  = (ushort_t*)(ws + 136921088);
  const size_t H4S = (size_t)512*196*96;      // per-s-half h4 elements

  k_wt<<<504, 256, 0, stream>>>(fc4_w1, fc4_w2, fc3_w1, fc3_w2,
                                w1t, w2t, w1t3, w2t3);
  // fused mean + fc1 + LN-stats (single pass over all four inputs)
  k_ms<<<2048, 384, 0, stream>>>(fq, fs, fqs, fss,
                                 fc1_w1, fc1_b1, fc1_w2, fc1_b2,
                                 mlp1, mu, rstd);
  k_class<<<1024, 384, 0, stream>>>(fq, fs, mlp1, mu, rstd, ln1_g, ln1_b, out);
  k_cosine<<<512, 384, 0, stream>>>(cs_w1, cs_b1, cs_w2, cs_b2, out);
  // fc3 fused MFMA: q-start then s-start
  k_fc3<<<3072, 256, 0, stream>>>(fqs, mlp1 + (size_t)2*512*384, mu + 2*100864, rstd + 2*100864,
                                  ln1_g, ln1_b, w1t3, fc3_b1, w2t3, fc3_b2, ln3_g, ln3_b, Qb);
  k_fc3<<<3072, 256, 0, stream>>>(fss, mlp1 + (size_t)3*512*384, mu + 3*100864, rstd + 3*100864,
                                  ln1_g, ln1_b, w1t3, fc3_b1, w2t3, fc3_b2, ln3_g, ln3_b, Sb);
  // fc4 stage A (MFMA): q then s (pre-offset pointers, no runtime s-select)
  k_fc4a<<<2048, 256, 0, stream>>>(fq, mlp1, mu, rstd, ln1_g, ln1_b,
                                   Qb, w1t, fc4_b1, h4);
  k_fc4a<<<2048, 256, 0, stream>>>(fs, mlp1 + (size_t)512*384, mu + 100864, rstd + 100864,
                                   ln1_g, ln1_b, Sb, w1t, fc4_b1, h4 + H4S);
  // fc4 stage B (MFMA): q then s (Qb/Sb overwritten in place after their last read)
  k_fc4b<<<2048, 256, 0, stream>>>(h4,       w2t, fc4_b2, ln4_g, ln4_b, out + 1024,          Qb);
  k_fc4b<<<2048, 256, 0, stream>>>(h4 + H4S, w2t, fc4_b2, ln4_g, ln4_b, out + 1024 + 196608, Sb);
  k_sim<<<8192, 256, 0, stream>>>(Qb, Sb, P);
  // fc2 head: split-K GEMM (896 blocks) + tiny reduce
  k_fc2a<<<896, 256, 0, stream>>>(P, fc2_w1, Cpart);
  k_fc2b<<<512, 256, 0, stream>>>(Cpart, fc2_b1, fc2_w2, fc2_b2, out);
}

// Round 18
// 1329.906 us; speedup vs baseline: 1.0358x; 1.0358x over previous
//
#include <hip/hip_runtime.h>
#include <math.h>

typedef unsigned short ushort_t;
typedef __attribute__((ext_vector_type(8))) short bf16x8;
typedef __attribute__((ext_vector_type(4))) float f32x4;

// ---------------- helpers ----------------
__device__ __forceinline__ float geluf(float x){
  return 0.5f*x*(1.0f+erff(x*0.70710678118654752440f));
}
__device__ __forceinline__ float bfu(unsigned int u){
  union { unsigned int i; float f; } v; v.i = (u & 0xffffu) << 16; return v.f;
}
__device__ __forceinline__ unsigned int f2b(float f){
  union { float f; unsigned int i; } v; v.f = f;
  unsigned int r = v.i + 0x7fffu + ((v.i >> 16) & 1u);
  return (r >> 16);
}

// Problem constants
// B=512, N=197, C=384, T=196 image tokens
// d_out layout (floats): out[512] | cosine[512] | query_class[512*384] | support_class[512*384]

// ---------------- A: fused mean + fc1 + LN-stats (one block per (s,b)) ----------------
// Round-17 fusion was traffic-optimal (FETCH ~= logical) but occupancy-collapsed:
// 384 thr = 6 waves/CU at 1 block/CU (LDS 161KB) -> 1.0 TB/s latency-bound.
// Fix: 768 threads = 12 waves/CU. LDS fits ONLY by overlaying the coefficient
// arrays (ms/hs/m1s, 3.4KB) onto red's 12.3KB after the column-sum reduction:
//   ms[tid*4..] == red[0][tid] bytes (same-thread RMW, race-free);
//   hs/m1s written after barriers that retire all red reads.
__global__ __launch_bounds__(768) void k_ms(
    const float* __restrict__ x0, const float* __restrict__ x1,
    const float* __restrict__ x2, const float* __restrict__ x3,
    const float* __restrict__ w1, const float* __restrict__ b1,
    const float* __restrict__ w2, const float* __restrict__ b2,
    float* __restrict__ mlp1, float* __restrict__ mu, float* __restrict__ rstd){
  __shared__ ushort_t Xb[197][384];   // 151,296 B bf16 copy of the tile
  __shared__ float4 red[8][96];       // 12,288 B; ms/hs/m1s overlay after use
  float* ms  = (float*)&red[0][0];    // 384 f  (red[0] bytes)
  float* hs  = ms + 384;              // 96 f   (red[1][0..23])
  float* m1s = hs + 96;               // 384 f  (red[1][24..95] + red[2][0..23])
  int sb = blockIdx.x;
  int s = sb >> 9, b = sb & 511;
  const float* x = (s==0)?x0:(s==1)?x1:(s==2)?x2:x3;
  int tid = threadIdx.x;
  int c4 = tid % 96, g = tid / 96;    // 8 row-groups x 96 float4-slots
  const float* p = x + ((size_t)b*197)*384 + c4*4;
  float4 a0 = {0.f,0.f,0.f,0.f}, a1 = {0.f,0.f,0.f,0.f};
  int t = g;
  for (; t + 8 < 197; t += 16){
    float4 v0 = *reinterpret_cast<const float4*>(p + (size_t)t*384);
    float4 v1 = *reinterpret_cast<const float4*>(p + (size_t)(t+8)*384);
    uint2 pk0; pk0.x = f2b(v0.x) | (f2b(v0.y)<<16); pk0.y = f2b(v0.z) | (f2b(v0.w)<<16);
    uint2 pk1; pk1.x = f2b(v1.x) | (f2b(v1.y)<<16); pk1.y = f2b(v1.z) | (f2b(v1.w)<<16);
    *reinterpret_cast<uint2*>(&Xb[t][c4*4]) = pk0;
    *reinterpret_cast<uint2*>(&Xb[t+8][c4*4]) = pk1;
    a0.x += v0.x; a0.y += v0.y; a0.z += v0.z; a0.w += v0.w;
    a1.x += v1.x; a1.y += v1.y; a1.z += v1.z; a1.w += v1.w;
  }
  if (t < 197){
    float4 v = *reinterpret_cast<const float4*>(p + (size_t)t*384);
    uint2 pk; pk.x = f2b(v.x) | (f2b(v.y)<<16); pk.y = f2b(v.z) | (f2b(v.w)<<16);
    *reinterpret_cast<uint2*>(&Xb[t][c4*4]) = pk;
    a0.x += v.x; a0.y += v.y; a0.z += v.z; a0.w += v.w;
  }
  a0.x += a1.x; a0.y += a1.y; a0.z += a1.z; a0.w += a1.w;
  red[g][c4] = a0;
  __syncthreads();
  // column means (over 197 tokens) -> ms (overlay on red[0]; same-thread bytes)
  if (tid < 96){
    float sx=0.f, sy=0.f, sz=0.f, sw=0.f;
    #pragma unroll
    for (int gg = 0; gg < 8; ++gg){
      float4 v = red[gg][tid];
      sx += v.x; sy += v.y; sz += v.z; sw += v.w;
    }
    ms[tid*4+0] = sx*(1.0f/197.0f);
    ms[tid*4+1] = sy*(1.0f/197.0f);
    ms[tid*4+2] = sz*(1.0f/197.0f);
    ms[tid*4+3] = sw*(1.0f/197.0f);
  }
  __syncthreads();
  // fc1 hidden (384 -> 96, gelu) -> hs (red reads all retired at the barrier)
  if (tid < 96){
    float a = b1[tid];
    for (int c = 0; c < 384; ++c) a += ms[c]*w1[c*96+tid];
    hs[tid] = geluf(a);
  }
  __syncthreads();
  // fc1 output (96 -> 384) -> m1s + global mlp1
  if (tid < 384){
    float a = b2[tid];
    for (int j = 0; j < 96; ++j) a += hs[j]*w2[j*384+tid];
    m1s[tid] = a;
    mlp1[(size_t)sb*384 + tid] = a;
  }
  __syncthreads();
  // per-row LN stats from bf16 LDS copy: 48 groups of 16 lanes, 5 sweeps
  int grp = tid >> 4, il = tid & 15;
  for (int it = 0; it < 5; ++it){
    int tr = it*48 + grp;
    if (tr < 197){
      float sum = 0.f, sq = 0.f;
      #pragma unroll
      for (int e = 0; e < 6; ++e){
        int c = il*4 + e*64;
        uint2 v = *reinterpret_cast<const uint2*>(&Xb[tr][c]);
        float q0 = bfu(v.x)      + m1s[c+0];
        float q1 = bfu(v.x>>16)  + m1s[c+1];
        float q2 = bfu(v.y)      + m1s[c+2];
        float q3 = bfu(v.y>>16)  + m1s[c+3];
        sum += q0+q1+q2+q3;
        sq  += q0*q0+q1*q1+q2*q2+q3*q3;
      }
      #pragma unroll
      for (int o=1;o<16;o<<=1){ sum += __shfl_xor(sum,o); sq += __shfl_xor(sq,o); }
      if (il == 0){
        int row = sb*197 + tr;
        float m = sum*(1.0f/384.0f);
        mu[row] = m;
        rstd[row] = rsqrtf(sq*(1.0f/384.0f) - m*m + 1e-5f);
      }
    }
  }
}

// ---------------- D: class token rows -> d_out ----------------
__global__ __launch_bounds__(384) void k_class(
    const float* __restrict__ x0, const float* __restrict__ x1,
    const float* __restrict__ mlp1, const float* __restrict__ mu,
    const float* __restrict__ rstd, const float* __restrict__ g1,
    const float* __restrict__ bb1, float* __restrict__ dout){
  int s = blockIdx.x >> 9, b = blockIdx.x & 511, c = threadIdx.x;
  const float* x = s ? x1 : x0;
  int srow = (s*512 + b)*197;
  float v = x[((size_t)b*197)*384 + c] + mlp1[((size_t)s*512+b)*384 + c];
  float y = (v - mu[srow])*rstd[srow]*g1[c] + bb1[c];
  dout[1024 + (size_t)s*196608 + (size_t)b*384 + c] = y;
}

// ---------------- E: cosine head on class tokens ----------------
__global__ __launch_bounds__(384) void k_cosine(
    const float* __restrict__ w1, const float* __restrict__ b1,
    const float* __restrict__ w2, const float* __restrict__ b2,
    float* __restrict__ dout){
  __shared__ float qrow[384], srw[384], hq[96], hs[96];
  __shared__ float rd0[384], rd1[384], rd2[384];
  int b = blockIdx.x, tid = threadIdx.x;
  qrow[tid] = dout[1024   + (size_t)b*384 + tid];
  srw[tid]  = dout[197632 + (size_t)b*384 + tid];
  __syncthreads();
  if (tid < 96){
    float a = b1[tid];
    for (int c=0;c<384;++c) a += qrow[c]*w1[c*96+tid];
    hq[tid] = geluf(a);
  } else if (tid < 192){
    int j = tid - 96;
    float a = b1[j];
    for (int c=0;c<384;++c) a += srw[c]*w1[c*96+j];
    hs[j] = geluf(a);
  }
  __syncthreads();
  float qx = b2[tid], sy = b2[tid];
  for (int j=0;j<96;++j){ qx += hq[j]*w2[j*384+tid]; sy += hs[j]*w2[j*384+tid]; }
  rd0[tid] = qx*sy; rd1[tid] = qx*qx; rd2[tid] = sy*sy;
  __syncthreads();
  if (tid < 64){
    float d=0.f,nq=0.f,ns=0.f;
    for (int i=tid;i<384;i+=64){ d+=rd0[i]; nq+=rd1[i]; ns+=rd2[i]; }
    #pragma unroll
    for (int o=32;o;o>>=1){ d+=__shfl_down(d,o); nq+=__shfl_down(nq,o); ns+=__shfl_down(ns,o); }
    if (tid==0) dout[512 + b] = d / (fmaxf(sqrtf(nq),1e-8f)*fmaxf(sqrtf(ns),1e-8f));
  }
}

// ---------------- W: weight prep (bf16 transposes, zero-padded) ----------------
// grid 504, block 256 (504*256 = 129024).
__global__ __launch_bounds__(256) void k_wt(
    const float* __restrict__ w1_4, const float* __restrict__ w2_4,
    const float* __restrict__ w1_3, const float* __restrict__ w2_3,
    ushort_t* __restrict__ w1t, ushort_t* __restrict__ w2t,
    ushort_t* __restrict__ w1t3, ushort_t* __restrict__ w2t3){
  int idx = blockIdx.x*256 + threadIdx.x;
  if (idx < 36864){
    int c = idx / 96, j = idx - c*96;
    w2t[idx] = (ushort_t)f2b(w2_4[(size_t)j*384 + c]);
  } else if (idx < 73728){
    int k = idx - 36864;
    int j = k / 384, c = k - j*384;
    w1t[k] = (ushort_t)f2b(w1_4[(size_t)c*96 + j]);
  } else if (idx < 102400){
    int k = idx - 73728;
    int j = k / 224, t = k - j*224;
    w1t3[k] = (t < 196) ? (ushort_t)f2b(w1_3[(size_t)t*128 + j]) : (ushort_t)0;
  } else {
    int k = idx - 102400;
    int tp = k / 128, j = k - tp*128;
    w2t3[k] = (tp < 196) ? (ushort_t)f2b(w2_3[(size_t)j*196 + tp]) : (ushort_t)0;
  }
}

// ---------------- F: fc3 fused MFMA (one s-half per launch) ----------------
// grid 512*6 (b, c-tile of 64), block 256 = 4 waves; wave = 16 c rows.
__global__ __launch_bounds__(256) void k_fc3(
    const float* __restrict__ x,         // fqs or fss
    const float* __restrict__ m1_base,   // mlp1 + s*512*384
    const float* __restrict__ mu_s,      // mu + s*100864
    const float* __restrict__ rstd_s,
    const float* __restrict__ g1, const float* __restrict__ bln1,
    const ushort_t* __restrict__ w1t3,   // [128][224] bf16
    const float* __restrict__ b1,        // fc3_b1 [128]
    const ushort_t* __restrict__ w2t3,   // [208][128] bf16
    const float* __restrict__ b2, const float* __restrict__ g3,
    const float* __restrict__ b3,
    ushort_t* __restrict__ Qout){        // Qb or Sb
  __shared__ ushort_t Xs[64][232];       // X^T tile; Hs overlays cols [0,128) per wave
  __shared__ ushort_t W2s[112][136];     // w2t3 half (17x16B stride: bank-safe)
  __shared__ float m1s[64], g1s[64], b1s[64];
  __shared__ float mus[196], rss[196];
  __shared__ float b1j[128];
  __shared__ float b2s[208], g3s[208], b3s[208];
  int bid = blockIdx.x;
  int b = bid/6, c0 = (bid%6)*64;
  int tid = threadIdx.x;
  // stage coefficients
  if (tid < 64){
    m1s[tid] = m1_base[(size_t)b*384 + c0 + tid];
    g1s[tid] = g1[c0+tid]; b1s[tid] = bln1[c0+tid];
  }
  if (tid < 128) b1j[tid] = b1[tid];
  if (tid < 196){ mus[tid] = mu_s[b*197 + tid + 1]; rss[tid] = rstd_s[b*197 + tid + 1]; }
  if (tid < 208){
    float bb=0.f, gg=0.f, b3v=0.f;
    if (tid < 196){ bb = b2[tid]; gg = g3[tid]; b3v = b3[tid]; }
    b2s[tid]=bb; g3s[tid]=gg; b3s[tid]=b3v;
  }
  // stage W2s part 1 (w2t3 rows 0..111)
  for (int i = tid; i < 112*16; i += 256){
    int r = i >> 4, q = i & 15;
    *reinterpret_cast<uint4*>(&W2s[r][q*8]) =
        *reinterpret_cast<const uint4*>(&w2t3[(size_t)r*128 + q*8]);
  }
  // zero the t-pad of Xs ([196,224) as uints; [224,232) never read)
  for (int i = tid; i < 64*14; i += 256){
    *reinterpret_cast<unsigned int*>(&Xs[i/14][196 + 2*(i%14)]) = 0u;
  }
  __syncthreads();
  // phase 1: stage LN'd X^T tile by t-pairs (98 tpairs x 16 c4-slots = 1568)
  for (int e = 0; e < 7; ++e){
    int idx = e*256 + tid;
    if (idx < 1568){
      int t2 = idx >> 4, c4 = idx & 15;
      int t0 = t2*2;
      const float* xr = &x[((size_t)b*197 + t0 + 1)*384 + c0 + c4*4];
      float4 xv0 = *reinterpret_cast<const float4*>(xr);
      float4 xv1 = *reinterpret_cast<const float4*>(xr + 384);
      float mu0 = mus[t0], rs0 = rss[t0], mu1 = mus[t0+1], rs1 = rss[t0+1];
      int c = c4*4;
      unsigned int u0 = f2b(((xv0.x + m1s[c+0]) - mu0)*rs0*g1s[c+0] + b1s[c+0])
                      | (f2b(((xv1.x + m1s[c+0]) - mu1)*rs1*g1s[c+0] + b1s[c+0]) << 16);
      unsigned int u1 = f2b(((xv0.y + m1s[c+1]) - mu0)*rs0*g1s[c+1] + b1s[c+1])
                      | (f2b(((xv1.y + m1s[c+1]) - mu1)*rs1*g1s[c+1] + b1s[c+1]) << 16);
      unsigned int u2 = f2b(((xv0.z + m1s[c+2]) - mu0)*rs0*g1s[c+2] + b1s[c+2])
                      | (f2b(((xv1.z + m1s[c+2]) - mu1)*rs1*g1s[c+2] + b1s[c+2]) << 16);
      unsigned int u3 = f2b(((xv0.w + m1s[c+3]) - mu0)*rs0*g1s[c+3] + b1s[c+3])
                      | (f2b(((xv1.w + m1s[c+3]) - mu1)*rs1*g1s[c+3] + b1s[c+3]) << 16);
      *reinterpret_cast<unsigned int*>(&Xs[c+0][t0]) = u0;
      *reinterpret_cast<unsigned int*>(&Xs[c+1][t0]) = u1;
      *reinterpret_cast<unsigned int*>(&Xs[c+2][t0]) = u2;
      *reinterpret_cast<unsigned int*>(&Xs[c+3][t0]) = u3;
    }
  }
  __syncthreads();
  int w = tid >> 6, lane = tid & 63;
  int cl = lane & 15, kg = lane >> 4;
  // GEMM1: h = gelu(Xt @ w1 + b1); A register double-buffered
  f32x4 hacc[8];
  #pragma unroll
  for (int jf=0;jf<8;++jf){ f32x4 z={0.f,0.f,0.f,0.f}; hacc[jf]=z; }
  const ushort_t* zrow = &Xs[w*16 + cl][kg*8];
  const ushort_t* abase = w1t3 + (size_t)cl*224 + kg*8;
  bf16x8 aC[8], aN[8];
  #pragma unroll
  for (int jf=0;jf<8;++jf)
    aC[jf] = *reinterpret_cast<const bf16x8*>(abase + jf*16*224);
  for (int kc = 0; kc < 7; ++kc){
    bf16x8 xb = *reinterpret_cast<const bf16x8*>(zrow + kc*32);
    if (kc < 6){
      #pragma unroll
      for (int jf=0;jf<8;++jf)
        aN[jf] = *reinterpret_cast<const bf16x8*>(abase + jf*16*224 + (kc+1)*32);
    }
    #pragma unroll
    for (int jf=0;jf<8;++jf)
      hacc[jf] = __builtin_amdgcn_mfma_f32_16x16x32_bf16(aC[jf], xb, hacc[jf], 0, 0, 0);
    #pragma unroll
    for (int jf=0;jf<8;++jf) aC[jf] = aN[jf];
  }
  // D: row = j = jf*16+kg*4+r, col = c = cl -> overlay into the wave's OWN Xs rows.
  #pragma unroll
  for (int jf=0;jf<8;++jf){
    f32x4 y = hacc[jf];
    int j0 = jf*16 + kg*4;
    uint2 pk;
    pk.x = f2b(geluf(y[0]+b1j[j0+0])) | (f2b(geluf(y[1]+b1j[j0+1]))<<16);
    pk.y = f2b(geluf(y[2]+b1j[j0+2])) | (f2b(geluf(y[3]+b1j[j0+3]))<<16);
    *reinterpret_cast<uint2*>(&Xs[w*16 + cl][j0]) = pk;
  }
  // GEMM2: y = h @ w2 (+b2 in epilogue); B from LDS in two halves
  f32x4 yacc[13];
  #pragma unroll
  for (int tf=0;tf<13;++tf){ f32x4 z={0.f,0.f,0.f,0.f}; yacc[tf]=z; }
  const ushort_t* hrow = &Xs[w*16 + cl][kg*8];
  // part A: tf 0..6 (t' rows 0..111 in W2s)
  for (int kc = 0; kc < 4; ++kc){
    bf16x8 hb = *reinterpret_cast<const bf16x8*>(hrow + kc*32);
    #pragma unroll
    for (int tf=0;tf<7;++tf){
      const ushort_t* bp = &W2s[tf*16 + cl][kg*8 + kc*32];
      yacc[tf] = __builtin_amdgcn_mfma_f32_16x16x32_bf16(
          hb, *reinterpret_cast<const bf16x8*>(bp), yacc[tf], 0, 0, 0);
    }
  }
  __syncthreads();
  // restage W2s with w2t3 rows 112..207 (96 rows)
  for (int i = tid; i < 96*16; i += 256){
    int r = i >> 4, q = i & 15;
    *reinterpret_cast<uint4*>(&W2s[r][q*8]) =
        *reinterpret_cast<const uint4*>(&w2t3[(size_t)(112 + r)*128 + q*8]);
  }
  __syncthreads();
  // part B: tf 7..12 (t' rows 112..207 -> W2s rows tf*16+cl-112)
  for (int kc = 0; kc < 4; ++kc){
    bf16x8 hb = *reinterpret_cast<const bf16x8*>(hrow + kc*32);
    #pragma unroll
    for (int tf=7;tf<13;++tf){
      const ushort_t* bp = &W2s[tf*16 + cl - 112][kg*8 + kc*32];
      yacc[tf] = __builtin_amdgcn_mfma_f32_16x16x32_bf16(
          hb, *reinterpret_cast<const bf16x8*>(bp), yacc[tf], 0, 0, 0);
    }
  }
  // epilogue: lane holds c = c0 + w*16 + kg*4 + r (r=0..3), t' = tf*16 + cl.
  float sum0=0.f,sum1=0.f,sum2=0.f,sum3=0.f, sq0=0.f,sq1=0.f,sq2=0.f,sq3=0.f;
  #pragma unroll
  for (int tf=0;tf<13;++tf){
    int tp = tf*16 + cl;
    float bb = b2s[tp];
    f32x4 y = yacc[tf];
    y[0]+=bb; y[1]+=bb; y[2]+=bb; y[3]+=bb;
    yacc[tf] = y;
    sum0+=y[0]; sum1+=y[1]; sum2+=y[2]; sum3+=y[3];
    sq0+=y[0]*y[0]; sq1+=y[1]*y[1]; sq2+=y[2]*y[2]; sq3+=y[3]*y[3];
  }
  #pragma unroll
  for (int o=1;o<16;o<<=1){
    sum0+=__shfl_xor(sum0,o); sum1+=__shfl_xor(sum1,o);
    sum2+=__shfl_xor(sum2,o); sum3+=__shfl_xor(sum3,o);
    sq0+=__shfl_xor(sq0,o); sq1+=__shfl_xor(sq1,o);
    sq2+=__shfl_xor(sq2,o); sq3+=__shfl_xor(sq3,o);
  }
  float m0=sum0*(1.0f/196.0f), m1v=sum1*(1.0f/196.0f), m2=sum2*(1.0f/196.0f), m3=sum3*(1.0f/196.0f);
  float r0=rsqrtf(sq0*(1.0f/196.0f)-m0*m0+1e-5f);
  float r1=rsqrtf(sq1*(1.0f/196.0f)-m1v*m1v+1e-5f);
  float r2=rsqrtf(sq2*(1.0f/196.0f)-m2*m2+1e-5f);
  float r3=rsqrtf(sq3*(1.0f/196.0f)-m3*m3+1e-5f);
  int cbase = c0 + w*16 + kg*4;
  #pragma unroll
  for (int tf=0;tf<13;++tf){
    int tp = tf*16 + cl;
    if (tp < 196){
      float gg = g3s[tp], bb3 = b3s[tp];
      f32x4 y = yacc[tf];
      unsigned int o0 = f2b((y[0]-m0)*r0*gg + bb3);
      unsigned int o1 = f2b((y[1]-m1v)*r1*gg + bb3);
      unsigned int o2 = f2b((y[2]-m2)*r2*gg + bb3);
      unsigned int o3 = f2b((y[3]-m3)*r3*gg + bb3);
      uint2 pk; pk.x = o0 | (o1<<16); pk.y = o2 | (o3<<16);
      *reinterpret_cast<uint2*>(&Qout[((size_t)b*196 + tp)*384 + cbase]) = pk;
    }
  }
}

// ---------------- H1: fc4 stage A (MFMA; one s-half per launch) ----------------
// grid 512*4 (b, t-tile of 64), block 256 = 4 waves; wave = 16 t x 96 j.
__global__ __launch_bounds__(256) void k_fc4a(
    const float* __restrict__ x,         // fq or fs
    const float* __restrict__ m1_base,   // mlp1 + s*512*384
    const float* __restrict__ mu_s,      // mu + s*100864
    const float* __restrict__ rstd_s,    // rstd + s*100864
    const float* __restrict__ g1, const float* __restrict__ bln1,
    const ushort_t* __restrict__ Qin,    // Qb or Sb
    const ushort_t* __restrict__ w1t,    // [96][384] bf16
    const float* __restrict__ b1mlp,
    ushort_t* __restrict__ h4s){         // h4 + s*512*196*96
  __shared__ ushort_t Zs[64][392];       // bf16 Z tile, padded stride
  __shared__ float m1s[384], g1s[384], b1s[384];
  __shared__ float mus[64], rss[64];
  __shared__ float b1m[96];
  int bid = blockIdx.x;
  int b = bid >> 2, tt0 = (bid & 3)*64;
  int tid = threadIdx.x;
  const float* m1 = m1_base + (size_t)b*384;
  for (int i = tid; i < 384; i += 256){ m1s[i] = m1[i]; g1s[i] = g1[i]; b1s[i] = bln1[i]; }
  if (tid < 96) b1m[tid] = b1mlp[tid];
  if (tid < 64){
    int t = tt0 + tid; int tc = t < 196 ? t : 195;
    mus[tid] = mu_s[b*197 + tc + 1]; rss[tid] = rstd_s[b*197 + tc + 1];
  }
  __syncthreads();
  // phase 1: Z build, 64 rows x 96 col4-slots = 6144 slots, 24 per thread
  for (int e = 0; e < 24; ++e){
    int v = e*256 + tid;
    int row = v/96, col4 = v - row*96;
    int t = tt0 + row; int tc = t < 196 ? t : 195;
    float valid = (t < 196) ? 1.f : 0.f;
    float4 xv = *reinterpret_cast<const float4*>(&x[((size_t)b*197 + tc + 1)*384 + col4*4]);
    uint2 qv = *reinterpret_cast<const uint2*>(&Qin[((size_t)b*196 + tc)*384 + col4*4]);
    float muv = mus[row], rsv = rss[row];
    int c = col4*4;
    float z0 = (((xv.x + m1s[c+0]) - muv)*rsv*g1s[c+0] + b1s[c+0]) * bfu(qv.x)      * valid;
    float z1 = (((xv.y + m1s[c+1]) - muv)*rsv*g1s[c+1] + b1s[c+1]) * bfu(qv.x>>16)  * valid;
    float z2 = (((xv.z + m1s[c+2]) - muv)*rsv*g1s[c+2] + b1s[c+2]) * bfu(qv.y)      * valid;
    float z3 = (((xv.w + m1s[c+3]) - muv)*rsv*g1s[c+3] + b1s[c+3]) * bfu(qv.y>>16)  * valid;
    uint2 pk; pk.x = f2b(z0) | (f2b(z1)<<16); pk.y = f2b(z2) | (f2b(z3)<<16);
    *reinterpret_cast<uint2*>(&Zs[row][col4*4]) = pk;
  }
  __syncthreads();
  // phase 2: MFMA GEMM1 (16t x 96j per wave, K=384)
  int w = tid >> 6, lane = tid & 63;
  int tr = tt0 + w*16 + (lane & 15);
  int kg = lane >> 4;
  f32x4 acc0 = {0.f,0.f,0.f,0.f}, acc1 = {0.f,0.f,0.f,0.f}, acc2 = {0.f,0.f,0.f,0.f};
  f32x4 acc3 = {0.f,0.f,0.f,0.f}, acc4 = {0.f,0.f,0.f,0.f}, acc5 = {0.f,0.f,0.f,0.f};
  const ushort_t* arow = w1t + (size_t)(lane & 15)*384 + kg*8;
  const ushort_t* zrow = &Zs[w*16 + (lane & 15)][kg*8];
  for (int kc = 0; kc < 12; ++kc){
    bf16x8 zb = *reinterpret_cast<const bf16x8*>(zrow + kc*32);
    bf16x8 a0 = *reinterpret_cast<const bf16x8*>(arow + kc*32);
    bf16x8 a1 = *reinterpret_cast<const bf16x8*>(arow + kc*32 + 16*384);
    bf16x8 a2 = *reinterpret_cast<const bf16x8*>(arow + kc*32 + 32*384);
    bf16x8 a3 = *reinterpret_cast<const bf16x8*>(arow + kc*32 + 48*384);
    bf16x8 a4 = *reinterpret_cast<const bf16x8*>(arow + kc*32 + 64*384);
    bf16x8 a5 = *reinterpret_cast<const bf16x8*>(arow + kc*32 + 80*384);
    acc0 = __builtin_amdgcn_mfma_f32_16x16x32_bf16(a0, zb, acc0, 0, 0, 0);
    acc1 = __builtin_amdgcn_mfma_f32_16x16x32_bf16(a1, zb, acc1, 0, 0, 0);
    acc2 = __builtin_amdgcn_mfma_f32_16x16x32_bf16(a2, zb, acc2, 0, 0, 0);
    acc3 = __builtin_amdgcn_mfma_f32_16x16x32_bf16(a3, zb, acc3, 0, 0, 0);
    acc4 = __builtin_amdgcn_mfma_f32_16x16x32_bf16(a4, zb, acc4, 0, 0, 0);
    acc5 = __builtin_amdgcn_mfma_f32_16x16x32_bf16(a5, zb, acc5, 0, 0, 0);
  }
  // epilogue: lane holds j = jb*16 + kg*4 + r (D row), t = tr (D col)
  if (tr < 196){
    ushort_t* dst = h4s + ((size_t)b*196 + tr)*96 + kg*4;
    #pragma unroll
    for (int jb = 0; jb < 6; ++jb){
      f32x4 y = (jb==0)?acc0:(jb==1)?acc1:(jb==2)?acc2:(jb==3)?acc3:(jb==4)?acc4:acc5;
      int j0 = jb*16 + kg*4;
      uint2 pk;
      pk.x = f2b(geluf(y[0]+b1m[j0+0])) | (f2b(geluf(y[1]+b1m[j0+1]))<<16);
      pk.y = f2b(geluf(y[2]+b1m[j0+2])) | (f2b(geluf(y[3]+b1m[j0+3]))<<16);
      *reinterpret_cast<uint2*>(dst + jb*16) = pk;
    }
  }
}

// ---------------- H2: fc4 stage B (MFMA; one s-half per launch) ----------------
// grid 512*4 (b, t-tile of 64), block 256 = 4 waves; wave = 16 t x 384 c.
__global__ __launch_bounds__(256) void k_fc4b(
    const ushort_t* __restrict__ h4s,    // h4 + s*512*196*96
    const ushort_t* __restrict__ w2t,    // [384][96] bf16
    const float* __restrict__ b2, const float* __restrict__ g4,
    const float* __restrict__ bb4,
    const float* __restrict__ cls_base,  // dout + 1024 + s*196608
    ushort_t* __restrict__ Qo){          // Qb or Sb
  __shared__ float b2s[384], g4s[384], b4s[384], cl_s[384];
  int bid = blockIdx.x;
  int b = bid >> 2, ttile = bid & 3;
  int tid = threadIdx.x, w = tid >> 6, lane = tid & 63;
  const float* cls = cls_base + (size_t)b*384;
  for (int i = tid; i < 384; i += 256){
    b2s[i] = b2[i]; g4s[i] = g4[i]; b4s[i] = bb4[i]; cl_s[i] = cls[i];
  }
  __syncthreads();
  int tr = ttile*64 + w*16 + (lane & 15);
  int trc = tr < 196 ? tr : 195;
  int kg = lane >> 4;
  const ushort_t* hp = h4s + ((size_t)b*196 + trc)*96 + kg*8;
  bf16x8 hb0 = *reinterpret_cast<const bf16x8*>(hp);
  bf16x8 hb1 = *reinterpret_cast<const bf16x8*>(hp + 32);
  bf16x8 hb2 = *reinterpret_cast<const bf16x8*>(hp + 64);
  const ushort_t* ap_base = w2t + (size_t)(lane & 15)*96 + kg*8;
  f32x4 acc[24];
  #pragma unroll
  for (int af = 0; af < 24; ++af){
    const ushort_t* ap = ap_base + (size_t)af*16*96;
    bf16x8 a0 = *reinterpret_cast<const bf16x8*>(ap);
    bf16x8 a1 = *reinterpret_cast<const bf16x8*>(ap + 32);
    bf16x8 a2 = *reinterpret_cast<const bf16x8*>(ap + 64);
    f32x4 z = {0.f,0.f,0.f,0.f};
    z = __builtin_amdgcn_mfma_f32_16x16x32_bf16(a0, hb0, z, 0, 0, 0);
    z = __builtin_amdgcn_mfma_f32_16x16x32_bf16(a1, hb1, z, 0, 0, 0);
    z = __builtin_amdgcn_mfma_f32_16x16x32_bf16(a2, hb2, z, 0, 0, 0);
    acc[af] = z;
  }
  // epilogue: lane holds c = af*16 + kg*4 + r  (r=0..3), t = tr (col)
  float sum = 0.f, sq = 0.f;
  #pragma unroll
  for (int af = 0; af < 24; ++af){
    int cb = af*16 + kg*4;
    float4 bv = *reinterpret_cast<const float4*>(&b2s[cb]);
    f32x4 y = acc[af];
    y[0] += bv.x; y[1] += bv.y; y[2] += bv.z; y[3] += bv.w;
    acc[af] = y;
    sum += y[0]+y[1]+y[2]+y[3];
    sq  += y[0]*y[0]+y[1]*y[1]+y[2]*y[2]+y[3]*y[3];
  }
  sum += __shfl_xor(sum, 16); sum += __shfl_xor(sum, 32);
  sq  += __shfl_xor(sq, 16);  sq  += __shfl_xor(sq, 32);
  float m4 = sum*(1.0f/384.0f);
  float rs = rsqrtf(sq*(1.0f/384.0f) - m4*m4 + 1e-5f);
  float s2 = 0.f;
  #pragma unroll
  for (int af = 0; af < 24; ++af){
    int cb = af*16 + kg*4;
    float4 gv = *reinterpret_cast<const float4*>(&g4s[cb]);
    float4 bb = *reinterpret_cast<const float4*>(&b4s[cb]);
    float4 cv = *reinterpret_cast<const float4*>(&cl_s[cb]);
    f32x4 y = acc[af];
    y[0] = (y[0]-m4)*rs*gv.x + bb.x + 0.5f*cv.x;
    y[1] = (y[1]-m4)*rs*gv.y + bb.y + 0.5f*cv.y;
    y[2] = (y[2]-m4)*rs*gv.z + bb.z + 0.5f*cv.z;
    y[3] = (y[3]-m4)*rs*gv.w + bb.w + 0.5f*cv.w;
    acc[af] = y;
    s2 += y[0]*y[0]+y[1]*y[1]+y[2]*y[2]+y[3]*y[3];
  }
  s2 += __shfl_xor(s2, 16); s2 += __shfl_xor(s2, 32);
  float inv = 1.0f/fmaxf(sqrtf(s2), 1e-12f);
  float sm = 0.f;
  #pragma unroll
  for (int af = 0; af < 24; ++af){
    f32x4 y = acc[af];
    y[0]*=inv; y[1]*=inv; y[2]*=inv; y[3]*=inv;
    acc[af] = y;
    sm += y[0]+y[1]+y[2]+y[3];
  }
  sm += __shfl_xor(sm, 16); sm += __shfl_xor(sm, 32);
  sm *= (1.0f/384.0f);
  if (tr < 196){
    ushort_t* dst = Qo + ((size_t)b*196 + tr)*384 + kg*4;
    #pragma unroll
    for (int af = 0; af < 24; ++af){
      f32x4 y = acc[af];
      uint2 pk;
      pk.x = f2b(y[0]-sm) | (f2b(y[1]-sm)<<16);
      pk.y = f2b(y[2]-sm) | (f2b(y[3]-sm)<<16);
      *reinterpret_cast<uint2*>(dst + af*16) = pk;
    }
  }
}

// ---------------- I: batched einsum + fused 2x2 pooling (MFMA) ----------------
// grid 512*16 (b, qt, st), block 256 = 4 waves; wave = 32x32 output tile.
// XCD-chunked bijective swizzle + register double-buffered fragments.
__global__ __launch_bounds__(256) void k_sim(
    const ushort_t* __restrict__ Q, const ushort_t* __restrict__ S,
    float* __restrict__ P){
  int bid0 = blockIdx.x;
  int bx = (bid0 & 7)*1024 + (bid0 >> 3);   // bijective: consecutive work-b per XCD
  int b = bx >> 4, qt = (bx >> 2) & 3, st = bx & 3;
  int tid = threadIdx.x;
  int w = tid >> 6, lane = tid & 63;
  int wr = w >> 1, wc = w & 1;
  int q0 = qt*64 + wr*32, s0 = st*64 + wc*32;
  int rrow = lane & 15, kg = lane >> 4;
  const ushort_t* Qb_ = Q + (size_t)b*196*384;
  const ushort_t* Sb_ = S + (size_t)b*196*384;
  int qr0 = min(q0 + rrow, 195), qr1 = min(q0 + 16 + rrow, 195);
  int sr0 = min(s0 + rrow, 195), sr1 = min(s0 + 16 + rrow, 195);
  const ushort_t* qp0 = Qb_ + (size_t)qr0*384 + kg*8;
  const ushort_t* qp1 = Qb_ + (size_t)qr1*384 + kg*8;
  const ushort_t* sp0 = Sb_ + (size_t)sr0*384 + kg*8;
  const ushort_t* sp1 = Sb_ + (size_t)sr1*384 + kg*8;
  f32x4 acc00 = {0.f,0.f,0.f,0.f}, acc01 = {0.f,0.f,0.f,0.f};
  f32x4 acc10 = {0.f,0.f,0.f,0.f}, acc11 = {0.f,0.f,0.f,0.f};
  bf16x8 qa0 = *reinterpret_cast<const bf16x8*>(qp0);
  bf16x8 qa1 = *reinterpret_cast<const bf16x8*>(qp1);
  bf16x8 sa0 = *reinterpret_cast<const bf16x8*>(sp0);
  bf16x8 sa1 = *reinterpret_cast<const bf16x8*>(sp1);
  for (int kc = 0; kc < 11; ++kc){
    int koff = (kc+1)*32;
    bf16x8 nq0 = *reinterpret_cast<const bf16x8*>(qp0 + koff);
    bf16x8 nq1 = *reinterpret_cast<const bf16x8*>(qp1 + koff);
    bf16x8 ns0 = *reinterpret_cast<const bf16x8*>(sp0 + koff);
    bf16x8 ns1 = *reinterpret_cast<const bf16x8*>(sp1 + koff);
    acc00 = __builtin_amdgcn_mfma_f32_16x16x32_bf16(qa0, sa0, acc00, 0, 0, 0);
    acc01 = __builtin_amdgcn_mfma_f32_16x16x32_bf16(qa0, sa1, acc01, 0, 0, 0);
    acc10 = __builtin_amdgcn_mfma_f32_16x16x32_bf16(qa1, sa0, acc10, 0, 0, 0);
    acc11 = __builtin_amdgcn_mfma_f32_16x16x32_bf16(qa1, sa1, acc11, 0, 0, 0);
    qa0 = nq0; qa1 = nq1; sa0 = ns0; sa1 = ns1;
  }
  acc00 = __builtin_amdgcn_mfma_f32_16x16x32_bf16(qa0, sa0, acc00, 0, 0, 0);
  acc01 = __builtin_amdgcn_mfma_f32_16x16x32_bf16(qa0, sa1, acc01, 0, 0, 0);
  acc10 = __builtin_amdgcn_mfma_f32_16x16x32_bf16(qa1, sa0, acc10, 0, 0, 0);
  acc11 = __builtin_amdgcn_mfma_f32_16x16x32_bf16(qa1, sa1, acc11, 0, 0, 0);
  int c = lane & 15, g = lane >> 4;
  float* Pb = P + (size_t)b*98*98;
  #pragma unroll
  for (int i = 0; i < 2; ++i){
    #pragma unroll
    for (int j = 0; j < 2; ++j){
      f32x4 v = (i==0) ? (j==0 ? acc00 : acc01) : (j==0 ? acc10 : acc11);
      float p0 = v[0] + v[1];   // rows 4g, 4g+1
      float p1 = v[2] + v[3];   // rows 4g+2, 4g+3
      float t0 = p0 + __shfl_xor(p0, 1);
      float t1 = p1 + __shfl_xor(p1, 1);
      if (!(c & 1)){
        int qp = (q0 + 16*i + 4*g) >> 1;
        int sp = (s0 + 16*j + c) >> 1;
        if (sp < 98){
          if (qp     < 98) Pb[(size_t)(qp    )*98 + sp] = 0.25f*t0;
          if (qp + 1 < 98) Pb[(size_t)(qp + 1)*98 + sp] = 0.25f*t1;
        }
      }
    }
  }
}

// ---------------- J1: fc2 split-K GEMM  Cpart[ks] = P2-chunk @ w1-chunk ----------------
// grid 64*14 (m-block of 8 rows, k-split of 686), block 256 (= N columns)
__global__ __launch_bounds__(256) void k_fc2a(
    const float* __restrict__ P, const float* __restrict__ w1,
    float* __restrict__ Cpart){
  __shared__ float p2[8][688];
  int bx = blockIdx.x;
  int mb = bx & 63, ks = bx >> 6;      // 14 k-splits of 686 (14*686 = 9604)
  int b0 = mb*8, k0 = ks*686;
  int tid = threadIdx.x;
  for (int idx = tid; idx < 8*686; idx += 256){
    int r = idx / 686, i = idx - r*686;
    float v = P[(size_t)(b0+r)*9604 + k0 + i];
    p2[r][i] = v*v;
  }
  __syncthreads();
  float acc[8];
  #pragma unroll
  for (int r=0;r<8;++r) acc[r]=0.f;
  for (int ii=0; ii<686; ++ii){
    float w = w1[(size_t)(k0+ii)*256 + tid];
    #pragma unroll
    for (int r=0;r<8;++r) acc[r] += p2[r][ii]*w;
  }
  #pragma unroll
  for (int r=0;r<8;++r) Cpart[((size_t)ks*512 + b0 + r)*256 + tid] = acc[r];
}

// ---------------- J2: fc2 reduce + gelu + w2 dot ----------------
// grid 512 (one b each), block 256
__global__ __launch_bounds__(256) void k_fc2b(
    const float* __restrict__ Cpart, const float* __restrict__ b1,
    const float* __restrict__ w2, const float* __restrict__ b2,
    float* __restrict__ outp){
  __shared__ float red[4];
  int b = blockIdx.x, tid = threadIdx.x;
  float s = 0.f;
  for (int ks = 0; ks < 14; ++ks) s += Cpart[((size_t)ks*512 + b)*256 + tid];
  float h = geluf(s + b1[tid]) * w2[tid];
  #pragma unroll
  for (int o=32;o;o>>=1) h += __shfl_down(h,o);
  int w = tid >> 6, lane = tid & 63;
  if (lane==0) red[w] = h;
  __syncthreads();
  if (tid==0) outp[b] = red[0]+red[1]+red[2]+red[3] + b2[0];
}

// ---------------- launch ----------------
extern "C" void kernel_launch(void* const* d_in, const int* in_sizes, int n_in,
                              void* d_out, int out_size, void* d_ws, size_t ws_size,
                              hipStream_t stream){
  const float* fq  = (const float*)d_in[0];
  const float* fs  = (const float*)d_in[1];
  const float* fqs = (const float*)d_in[2];
  const float* fss = (const float*)d_in[3];
  const float* fc1_w1 = (const float*)d_in[4];
  const float* fc1_b1 = (const float*)d_in[5];
  const float* fc1_w2 = (const float*)d_in[6];
  const float* fc1_b2 = (const float*)d_in[7];
  const float* ln1_g = (const float*)d_in[8];
  const float* ln1_b = (const float*)d_in[9];
  const float* fc3_w1 = (const float*)d_in[10];
  const float* fc3_b1 = (const float*)d_in[11];
  const float* fc3_w2 = (const float*)d_in[12];
  const float* fc3_b2 = (const float*)d_in[13];
  const float* ln3_g = (const float*)d_in[14];
  const float* ln3_b = (const float*)d_in[15];
  const float* fc4_w1 = (const float*)d_in[16];
  const float* fc4_b1 = (const float*)d_in[17];
  const float* fc4_w2 = (const float*)d_in[18];
  const float* fc4_b2 = (const float*)d_in[19];
  const float* ln4_g = (const float*)d_in[20];
  const float* ln4_b = (const float*)d_in[21];
  const float* fc2_w1 = (const float*)d_in[22];
  const float* fc2_b1 = (const float*)d_in[23];
  const float* fc2_w2 = (const float*)d_in[24];
  const float* fc2_b2 = (const float*)d_in[25];
  const float* cs_w1 = (const float*)d_in[26];
  const float* cs_b1 = (const float*)d_in[27];
  const float* cs_w2 = (const float*)d_in[28];
  const float* cs_b2 = (const float*)d_in[29];
  float* out = (float*)d_out;
  char* ws = (char*)d_ws;
  // ws layout (bytes):
  //   w2t  bf16 @0          (73,728)      [fc4 w2^T]
  //   w1t  bf16 @73728      (73,728)      [fc4 w1^T]
  //   w1t3 bf16 @147456     (57,344)      [fc3 w1^T, t-pad 224]
  //   w2t3 bf16 @204800     (53,248)      [fc3 w2^T, t'-pad 208]
  //   mlp1  f32 @3145728    (3,145,728)
  //   mu    f32 @6291456    (1,613,824)
  //   rstd  f32 @7905280    (1,613,824)
  //   h4    bf16 @9519104   (38,535,168)  [then P f32 + Cpart overlay]
  //   P     f32 @9519104    (19,668,992)  [overlays h4 (dead after fc4b)]
  //   Cpart f32 @29188096   (7,340,032)
  //   Qb    bf16 @59850752  (77,070,336)
  //   Sb    bf16 @136921088 (77,070,336)
  //   total 213,991,424 B
  ushort_t* w2t  = (ushort_t*)(ws + 0);
  ushort_t* w1t  = (ushort_t*)(ws + 73728);
  ushort_t* w1t3 = (ushort_t*)(ws + 147456);
  ushort_t* w2t3 = (ushort_t*)(ws + 204800);
  float* mlp1   = (float*)(ws + 3145728);
  float* mu     = (float*)(ws + 6291456);
  float* rstd   = (float*)(ws + 7905280);
  ushort_t* h4  = (ushort_t*)(ws + 9519104);
  float* P      = (float*)(ws + 9519104);     // overlays h4 (dead after fc4b)
  float* Cpart  = (float*)(ws + 29188096);    // after P, before Qb
  ushort_t* Qb  = (ushort_t*)(ws + 59850752);
  ushort_t* Sb  = (ushort_t*)(ws + 136921088);
  const size_t H4S = (size_t)512*196*96;      // per-s-half h4 elements

  k_wt<<<504, 256, 0, stream>>>(fc4_w1, fc4_w2, fc3_w1, fc3_w2,
                                w1t, w2t, w1t3, w2t3);
  // fused mean + fc1 + LN-stats (single pass over all four inputs; 12 waves/CU)
  k_ms<<<2048, 768, 0, stream>>>(fq, fs, fqs, fss,
                                 fc1_w1, fc1_b1, fc1_w2, fc1_b2,
                                 mlp1, mu, rstd);
  k_class<<<1024, 384, 0, stream>>>(fq, fs, mlp1, mu, rstd, ln1_g, ln1_b, out);
  k_cosine<<<512, 384, 0, stream>>>(cs_w1, cs_b1, cs_w2, cs_b2, out);
  // fc3 fused MFMA: q-start then s-start
  k_fc3<<<3072, 256, 0, stream>>>(fqs, mlp1 + (size_t)2*512*384, mu + 2*100864, rstd + 2*100864,
                                  ln1_g, ln1_b, w1t3, fc3_b1, w2t3, fc3_b2, ln3_g, ln3_b, Qb);
  k_fc3<<<3072, 256, 0, stream>>>(fss, mlp1 + (size_t)3*512*384, mu + 3*100864, rstd + 3*100864,
                                  ln1_g, ln1_b, w1t3, fc3_b1, w2t3, fc3_b2, ln3_g, ln3_b, Sb);
  // fc4 stage A (MFMA): q then s (pre-offset pointers, no runtime s-select)
  k_fc4a<<<2048, 256, 0, stream>>>(fq, mlp1, mu, rstd, ln1_g, ln1_b,
                                   Qb, w1t, fc4_b1, h4);
  k_fc4a<<<2048, 256, 0, stream>>>(fs, mlp1 + (size_t)512*384, mu + 100864, rstd + 100864,
                                   ln1_g, ln1_b, Sb, w1t, fc4_b1, h4 + H4S);
  // fc4 stage B (MFMA): q then s (Qb/Sb overwritten in place after their last read)
  k_fc4b<<<2048, 256, 0, stream>>>(h4,       w2t, fc4_b2, ln4_g, ln4_b, out + 1024,          Qb);
  k_fc4b<<<2048, 256, 0, stream>>>(h4 + H4S, w2t, fc4_b2, ln4_g, ln4_b, out + 1024 + 196608, Sb);
  k_sim<<<8192, 256, 0, stream>>>(Qb, Sb, P);
  // fc2 head: split-K GEMM (896 blocks) + tiny reduce
  k_fc2a<<<896, 256, 0, stream>>>(P, fc2_w1, Cpart);
  k_fc2b<<<512, 256, 0, stream>>>(Cpart, fc2_b1, fc2_w2, fc2_b2, out);
}

// Round 19
// 1317.574 us; speedup vs baseline: 1.0455x; 1.0094x over previous
//
#include <hip/hip_runtime.h>
#include <math.h>

typedef unsigned short ushort_t;
typedef __attribute__((ext_vector_type(8))) short bf16x8;
typedef __attribute__((ext_vector_type(4))) float f32x4;

// ---------------- helpers ----------------
__device__ __forceinline__ float geluf(float x){
  return 0.5f*x*(1.0f+erff(x*0.70710678118654752440f));
}
__device__ __forceinline__ float bfu(unsigned int u){
  union { unsigned int i; float f; } v; v.i = (u & 0xffffu) << 16; return v.f;
}
__device__ __forceinline__ unsigned int f2b(float f){
  union { float f; unsigned int i; } v; v.f = f;
  unsigned int r = v.i + 0x7fffu + ((v.i >> 16) & 1u);
  return (r >> 16);
}

// Problem constants
// B=512, N=197, C=384, T=196 image tokens
// d_out layout (floats): out[512] | cosine[512] | query_class[512*384] | support_class[512*384]

// ---------------- A: fused mean + fc1 + LN-stats (one block per (s,b)) ----------------
__global__ __launch_bounds__(768) void k_ms(
    const float* __restrict__ x0, const float* __restrict__ x1,
    const float* __restrict__ x2, const float* __restrict__ x3,
    const float* __restrict__ w1, const float* __restrict__ b1,
    const float* __restrict__ w2, const float* __restrict__ b2,
    float* __restrict__ mlp1, float* __restrict__ mu, float* __restrict__ rstd){
  __shared__ ushort_t Xb[197][384];   // 151,296 B bf16 copy of the tile
  __shared__ float4 red[8][96];       // 12,288 B; ms/hs/m1s overlay after use
  float* ms  = (float*)&red[0][0];    // 384 f  (red[0] bytes)
  float* hs  = ms + 384;              // 96 f
  float* m1s = hs + 96;               // 384 f
  int sb = blockIdx.x;
  int s = sb >> 9, b = sb & 511;
  const float* x = (s==0)?x0:(s==1)?x1:(s==2)?x2:x3;
  int tid = threadIdx.x;
  int c4 = tid % 96, g = tid / 96;    // 8 row-groups x 96 float4-slots
  const float* p = x + ((size_t)b*197)*384 + c4*4;
  float4 a0 = {0.f,0.f,0.f,0.f}, a1 = {0.f,0.f,0.f,0.f};
  int t = g;
  for (; t + 8 < 197; t += 16){
    float4 v0 = *reinterpret_cast<const float4*>(p + (size_t)t*384);
    float4 v1 = *reinterpret_cast<const float4*>(p + (size_t)(t+8)*384);
    uint2 pk0; pk0.x = f2b(v0.x) | (f2b(v0.y)<<16); pk0.y = f2b(v0.z) | (f2b(v0.w)<<16);
    uint2 pk1; pk1.x = f2b(v1.x) | (f2b(v1.y)<<16); pk1.y = f2b(v1.z) | (f2b(v1.w)<<16);
    *reinterpret_cast<uint2*>(&Xb[t][c4*4]) = pk0;
    *reinterpret_cast<uint2*>(&Xb[t+8][c4*4]) = pk1;
    a0.x += v0.x; a0.y += v0.y; a0.z += v0.z; a0.w += v0.w;
    a1.x += v1.x; a1.y += v1.y; a1.z += v1.z; a1.w += v1.w;
  }
  if (t < 197){
    float4 v = *reinterpret_cast<const float4*>(p + (size_t)t*384);
    uint2 pk; pk.x = f2b(v.x) | (f2b(v.y)<<16); pk.y = f2b(v.z) | (f2b(v.w)<<16);
    *reinterpret_cast<uint2*>(&Xb[t][c4*4]) = pk;
    a0.x += v.x; a0.y += v.y; a0.z += v.z; a0.w += v.w;
  }
  a0.x += a1.x; a0.y += a1.y; a0.z += a1.z; a0.w += a1.w;
  red[g][c4] = a0;
  __syncthreads();
  if (tid < 96){
    float sx=0.f, sy=0.f, sz=0.f, sw=0.f;
    #pragma unroll
    for (int gg = 0; gg < 8; ++gg){
      float4 v = red[gg][tid];
      sx += v.x; sy += v.y; sz += v.z; sw += v.w;
    }
    ms[tid*4+0] = sx*(1.0f/197.0f);
    ms[tid*4+1] = sy*(1.0f/197.0f);
    ms[tid*4+2] = sz*(1.0f/197.0f);
    ms[tid*4+3] = sw*(1.0f/197.0f);
  }
  __syncthreads();
  if (tid < 96){
    float a = b1[tid];
    for (int c = 0; c < 384; ++c) a += ms[c]*w1[c*96+tid];
    hs[tid] = geluf(a);
  }
  __syncthreads();
  if (tid < 384){
    float a = b2[tid];
    for (int j = 0; j < 96; ++j) a += hs[j]*w2[j*384+tid];
    m1s[tid] = a;
    mlp1[(size_t)sb*384 + tid] = a;
  }
  __syncthreads();
  int grp = tid >> 4, il = tid & 15;
  for (int it = 0; it < 5; ++it){
    int tr = it*48 + grp;
    if (tr < 197){
      float sum = 0.f, sq = 0.f;
      #pragma unroll
      for (int e = 0; e < 6; ++e){
        int c = il*4 + e*64;
        uint2 v = *reinterpret_cast<const uint2*>(&Xb[tr][c]);
        float q0 = bfu(v.x)      + m1s[c+0];
        float q1 = bfu(v.x>>16)  + m1s[c+1];
        float q2 = bfu(v.y)      + m1s[c+2];
        float q3 = bfu(v.y>>16)  + m1s[c+3];
        sum += q0+q1+q2+q3;
        sq  += q0*q0+q1*q1+q2*q2+q3*q3;
      }
      #pragma unroll
      for (int o=1;o<16;o<<=1){ sum += __shfl_xor(sum,o); sq += __shfl_xor(sq,o); }
      if (il == 0){
        int row = sb*197 + tr;
        float m = sum*(1.0f/384.0f);
        mu[row] = m;
        rstd[row] = rsqrtf(sq*(1.0f/384.0f) - m*m + 1e-5f);
      }
    }
  }
}

// ---------------- D: class token rows -> d_out ----------------
__global__ __launch_bounds__(384) void k_class(
    const float* __restrict__ x0, const float* __restrict__ x1,
    const float* __restrict__ mlp1, const float* __restrict__ mu,
    const float* __restrict__ rstd, const float* __restrict__ g1,
    const float* __restrict__ bb1, float* __restrict__ dout){
  int s = blockIdx.x >> 9, b = blockIdx.x & 511, c = threadIdx.x;
  const float* x = s ? x1 : x0;
  int srow = (s*512 + b)*197;
  float v = x[((size_t)b*197)*384 + c] + mlp1[((size_t)s*512+b)*384 + c];
  float y = (v - mu[srow])*rstd[srow]*g1[c] + bb1[c];
  dout[1024 + (size_t)s*196608 + (size_t)b*384 + c] = y;
}

// ---------------- E: cosine head on class tokens ----------------
__global__ __launch_bounds__(384) void k_cosine(
    const float* __restrict__ w1, const float* __restrict__ b1,
    const float* __restrict__ w2, const float* __restrict__ b2,
    float* __restrict__ dout){
  __shared__ float qrow[384], srw[384], hq[96], hs[96];
  __shared__ float rd0[384], rd1[384], rd2[384];
  int b = blockIdx.x, tid = threadIdx.x;
  qrow[tid] = dout[1024   + (size_t)b*384 + tid];
  srw[tid]  = dout[197632 + (size_t)b*384 + tid];
  __syncthreads();
  if (tid < 96){
    float a = b1[tid];
    for (int c=0;c<384;++c) a += qrow[c]*w1[c*96+tid];
    hq[tid] = geluf(a);
  } else if (tid < 192){
    int j = tid - 96;
    float a = b1[j];
    for (int c=0;c<384;++c) a += srw[c]*w1[c*96+j];
    hs[j] = geluf(a);
  }
  __syncthreads();
  float qx = b2[tid], sy = b2[tid];
  for (int j=0;j<96;++j){ qx += hq[j]*w2[j*384+tid]; sy += hs[j]*w2[j*384+tid]; }
  rd0[tid] = qx*sy; rd1[tid] = qx*qx; rd2[tid] = sy*sy;
  __syncthreads();
  if (tid < 64){
    float d=0.f,nq=0.f,ns=0.f;
    for (int i=tid;i<384;i+=64){ d+=rd0[i]; nq+=rd1[i]; ns+=rd2[i]; }
    #pragma unroll
    for (int o=32;o;o>>=1){ d+=__shfl_down(d,o); nq+=__shfl_down(nq,o); ns+=__shfl_down(ns,o); }
    if (tid==0) dout[512 + b] = d / (fmaxf(sqrtf(nq),1e-8f)*fmaxf(sqrtf(ns),1e-8f));
  }
}

// ---------------- W: weight prep (bf16 transposes, zero-padded) ----------------
__global__ __launch_bounds__(256) void k_wt(
    const float* __restrict__ w1_4, const float* __restrict__ w2_4,
    const float* __restrict__ w1_3, const float* __restrict__ w2_3,
    ushort_t* __restrict__ w1t, ushort_t* __restrict__ w2t,
    ushort_t* __restrict__ w1t3, ushort_t* __restrict__ w2t3){
  int idx = blockIdx.x*256 + threadIdx.x;
  if (idx < 36864){
    int c = idx / 96, j = idx - c*96;
    w2t[idx] = (ushort_t)f2b(w2_4[(size_t)j*384 + c]);
  } else if (idx < 73728){
    int k = idx - 36864;
    int j = k / 384, c = k - j*384;
    w1t[k] = (ushort_t)f2b(w1_4[(size_t)c*96 + j]);
  } else if (idx < 102400){
    int k = idx - 73728;
    int j = k / 224, t = k - j*224;
    w1t3[k] = (t < 196) ? (ushort_t)f2b(w1_3[(size_t)t*128 + j]) : (ushort_t)0;
  } else {
    int k = idx - 102400;
    int tp = k / 128, j = k - tp*128;
    w2t3[k] = (tp < 196) ? (ushort_t)f2b(w2_3[(size_t)j*196 + tp]) : (ushort_t)0;
  }
}

// ---------------- F: fc3 fused MFMA (q+s merged; grid 6144) ----------------
// s = bid>=3072 (block-uniform SGPR select); q-half writes Qb, s-half Sb.
__global__ __launch_bounds__(256) void k_fc3(
    const float* __restrict__ xq, const float* __restrict__ xs,
    const float* __restrict__ mlp1, const float* __restrict__ mu,
    const float* __restrict__ rstd,
    const float* __restrict__ g1, const float* __restrict__ bln1,
    const ushort_t* __restrict__ w1t3,   // [128][224] bf16
    const float* __restrict__ b1,        // fc3_b1 [128]
    const ushort_t* __restrict__ w2t3,   // [208][128] bf16
    const float* __restrict__ b2, const float* __restrict__ g3,
    const float* __restrict__ b3,
    ushort_t* __restrict__ Qb, ushort_t* __restrict__ Sb){
  __shared__ ushort_t Xs[64][232];       // X^T tile; Hs overlays cols [0,128) per wave
  __shared__ ushort_t W2s[112][136];     // w2t3 half (17x16B stride: bank-safe)
  __shared__ float m1s[64], g1s[64], b1s[64];
  __shared__ float mus[196], rss[196];
  __shared__ float b1j[128];
  __shared__ float b2s[208], g3s[208], b3s[208];
  int bid = blockIdx.x;
  int sh = bid >= 3072; bid -= sh*3072;
  const float* x = sh ? xs : xq;
  const float* m1_base = mlp1 + (size_t)(2+sh)*512*384;
  const float* mu_s = mu + (size_t)(2+sh)*100864;
  const float* rstd_s = rstd + (size_t)(2+sh)*100864;
  ushort_t* Qout = sh ? Sb : Qb;
  int b = bid/6, c0 = (bid%6)*64;
  int tid = threadIdx.x;
  // stage coefficients
  if (tid < 64){
    m1s[tid] = m1_base[(size_t)b*384 + c0 + tid];
    g1s[tid] = g1[c0+tid]; b1s[tid] = bln1[c0+tid];
  }
  if (tid < 128) b1j[tid] = b1[tid];
  if (tid < 196){ mus[tid] = mu_s[b*197 + tid + 1]; rss[tid] = rstd_s[b*197 + tid + 1]; }
  if (tid < 208){
    float bb=0.f, gg=0.f, b3v=0.f;
    if (tid < 196){ bb = b2[tid]; gg = g3[tid]; b3v = b3[tid]; }
    b2s[tid]=bb; g3s[tid]=gg; b3s[tid]=b3v;
  }
  // stage W2s part 1 (w2t3 rows 0..111)
  for (int i = tid; i < 112*16; i += 256){
    int r = i >> 4, q = i & 15;
    *reinterpret_cast<uint4*>(&W2s[r][q*8]) =
        *reinterpret_cast<const uint4*>(&w2t3[(size_t)r*128 + q*8]);
  }
  // zero the t-pad of Xs
  for (int i = tid; i < 64*14; i += 256){
    *reinterpret_cast<unsigned int*>(&Xs[i/14][196 + 2*(i%14)]) = 0u;
  }
  __syncthreads();
  // phase 1: stage LN'd X^T tile by t-pairs
  for (int e = 0; e < 7; ++e){
    int idx = e*256 + tid;
    if (idx < 1568){
      int t2 = idx >> 4, c4 = idx & 15;
      int t0 = t2*2;
      const float* xr = &x[((size_t)b*197 + t0 + 1)*384 + c0 + c4*4];
      float4 xv0 = *reinterpret_cast<const float4*>(xr);
      float4 xv1 = *reinterpret_cast<const float4*>(xr + 384);
      float mu0 = mus[t0], rs0 = rss[t0], mu1 = mus[t0+1], rs1 = rss[t0+1];
      int c = c4*4;
      unsigned int u0 = f2b(((xv0.x + m1s[c+0]) - mu0)*rs0*g1s[c+0] + b1s[c+0])
                      | (f2b(((xv1.x + m1s[c+0]) - mu1)*rs1*g1s[c+0] + b1s[c+0]) << 16);
      unsigned int u1 = f2b(((xv0.y + m1s[c+1]) - mu0)*rs0*g1s[c+1] + b1s[c+1])
                      | (f2b(((xv1.y + m1s[c+1]) - mu1)*rs1*g1s[c+1] + b1s[c+1]) << 16);
      unsigned int u2 = f2b(((xv0.z + m1s[c+2]) - mu0)*rs0*g1s[c+2] + b1s[c+2])
                      | (f2b(((xv1.z + m1s[c+2]) - mu1)*rs1*g1s[c+2] + b1s[c+2]) << 16);
      unsigned int u3 = f2b(((xv0.w + m1s[c+3]) - mu0)*rs0*g1s[c+3] + b1s[c+3])
                      | (f2b(((xv1.w + m1s[c+3]) - mu1)*rs1*g1s[c+3] + b1s[c+3]) << 16);
      *reinterpret_cast<unsigned int*>(&Xs[c+0][t0]) = u0;
      *reinterpret_cast<unsigned int*>(&Xs[c+1][t0]) = u1;
      *reinterpret_cast<unsigned int*>(&Xs[c+2][t0]) = u2;
      *reinterpret_cast<unsigned int*>(&Xs[c+3][t0]) = u3;
    }
  }
  __syncthreads();
  int w = tid >> 6, lane = tid & 63;
  int cl = lane & 15, kg = lane >> 4;
  // GEMM1: h = gelu(Xt @ w1 + b1); A register double-buffered
  f32x4 hacc[8];
  #pragma unroll
  for (int jf=0;jf<8;++jf){ f32x4 z={0.f,0.f,0.f,0.f}; hacc[jf]=z; }
  const ushort_t* zrow = &Xs[w*16 + cl][kg*8];
  const ushort_t* abase = w1t3 + (size_t)cl*224 + kg*8;
  bf16x8 aC[8], aN[8];
  #pragma unroll
  for (int jf=0;jf<8;++jf)
    aC[jf] = *reinterpret_cast<const bf16x8*>(abase + jf*16*224);
  for (int kc = 0; kc < 7; ++kc){
    bf16x8 xb = *reinterpret_cast<const bf16x8*>(zrow + kc*32);
    if (kc < 6){
      #pragma unroll
      for (int jf=0;jf<8;++jf)
        aN[jf] = *reinterpret_cast<const bf16x8*>(abase + jf*16*224 + (kc+1)*32);
    }
    #pragma unroll
    for (int jf=0;jf<8;++jf)
      hacc[jf] = __builtin_amdgcn_mfma_f32_16x16x32_bf16(aC[jf], xb, hacc[jf], 0, 0, 0);
    #pragma unroll
    for (int jf=0;jf<8;++jf) aC[jf] = aN[jf];
  }
  // overlay h into the wave's OWN Xs rows (wave-local, no barrier needed)
  #pragma unroll
  for (int jf=0;jf<8;++jf){
    f32x4 y = hacc[jf];
    int j0 = jf*16 + kg*4;
    uint2 pk;
    pk.x = f2b(geluf(y[0]+b1j[j0+0])) | (f2b(geluf(y[1]+b1j[j0+1]))<<16);
    pk.y = f2b(geluf(y[2]+b1j[j0+2])) | (f2b(geluf(y[3]+b1j[j0+3]))<<16);
    *reinterpret_cast<uint2*>(&Xs[w*16 + cl][j0]) = pk;
  }
  // GEMM2: y = h @ w2 (+b2 in epilogue); B from LDS in two halves
  f32x4 yacc[13];
  #pragma unroll
  for (int tf=0;tf<13;++tf){ f32x4 z={0.f,0.f,0.f,0.f}; yacc[tf]=z; }
  const ushort_t* hrow = &Xs[w*16 + cl][kg*8];
  for (int kc = 0; kc < 4; ++kc){
    bf16x8 hb = *reinterpret_cast<const bf16x8*>(hrow + kc*32);
    #pragma unroll
    for (int tf=0;tf<7;++tf){
      const ushort_t* bp = &W2s[tf*16 + cl][kg*8 + kc*32];
      yacc[tf] = __builtin_amdgcn_mfma_f32_16x16x32_bf16(
          hb, *reinterpret_cast<const bf16x8*>(bp), yacc[tf], 0, 0, 0);
    }
  }
  __syncthreads();
  for (int i = tid; i < 96*16; i += 256){
    int r = i >> 4, q = i & 15;
    *reinterpret_cast<uint4*>(&W2s[r][q*8]) =
        *reinterpret_cast<const uint4*>(&w2t3[(size_t)(112 + r)*128 + q*8]);
  }
  __syncthreads();
  for (int kc = 0; kc < 4; ++kc){
    bf16x8 hb = *reinterpret_cast<const bf16x8*>(hrow + kc*32);
    #pragma unroll
    for (int tf=7;tf<13;++tf){
      const ushort_t* bp = &W2s[tf*16 + cl - 112][kg*8 + kc*32];
      yacc[tf] = __builtin_amdgcn_mfma_f32_16x16x32_bf16(
          hb, *reinterpret_cast<const bf16x8*>(bp), yacc[tf], 0, 0, 0);
    }
  }
  // epilogue: bias + LN over t' + write
  float sum0=0.f,sum1=0.f,sum2=0.f,sum3=0.f, sq0=0.f,sq1=0.f,sq2=0.f,sq3=0.f;
  #pragma unroll
  for (int tf=0;tf<13;++tf){
    int tp = tf*16 + cl;
    float bb = b2s[tp];
    f32x4 y = yacc[tf];
    y[0]+=bb; y[1]+=bb; y[2]+=bb; y[3]+=bb;
    yacc[tf] = y;
    sum0+=y[0]; sum1+=y[1]; sum2+=y[2]; sum3+=y[3];
    sq0+=y[0]*y[0]; sq1+=y[1]*y[1]; sq2+=y[2]*y[2]; sq3+=y[3]*y[3];
  }
  #pragma unroll
  for (int o=1;o<16;o<<=1){
    sum0+=__shfl_xor(sum0,o); sum1+=__shfl_xor(sum1,o);
    sum2+=__shfl_xor(sum2,o); sum3+=__shfl_xor(sum3,o);
    sq0+=__shfl_xor(sq0,o); sq1+=__shfl_xor(sq1,o);
    sq2+=__shfl_xor(sq2,o); sq3+=__shfl_xor(sq3,o);
  }
  float m0=sum0*(1.0f/196.0f), m1v=sum1*(1.0f/196.0f), m2=sum2*(1.0f/196.0f), m3=sum3*(1.0f/196.0f);
  float r0=rsqrtf(sq0*(1.0f/196.0f)-m0*m0+1e-5f);
  float r1=rsqrtf(sq1*(1.0f/196.0f)-m1v*m1v+1e-5f);
  float r2=rsqrtf(sq2*(1.0f/196.0f)-m2*m2+1e-5f);
  float r3=rsqrtf(sq3*(1.0f/196.0f)-m3*m3+1e-5f);
  int cbase = c0 + w*16 + kg*4;
  #pragma unroll
  for (int tf=0;tf<13;++tf){
    int tp = tf*16 + cl;
    if (tp < 196){
      float gg = g3s[tp], bb3 = b3s[tp];
      f32x4 y = yacc[tf];
      unsigned int o0 = f2b((y[0]-m0)*r0*gg + bb3);
      unsigned int o1 = f2b((y[1]-m1v)*r1*gg + bb3);
      unsigned int o2 = f2b((y[2]-m2)*r2*gg + bb3);
      unsigned int o3 = f2b((y[3]-m3)*r3*gg + bb3);
      uint2 pk; pk.x = o0 | (o1<<16); pk.y = o2 | (o3<<16);
      *reinterpret_cast<uint2*>(&Qout[((size_t)b*196 + tp)*384 + cbase]) = pk;
    }
  }
}

// ---------------- H1: fc4 stage A (q+s merged; grid 4096) ----------------
__global__ __launch_bounds__(256) void k_fc4a(
    const float* __restrict__ xq, const float* __restrict__ xs,
    const float* __restrict__ mlp1, const float* __restrict__ mu,
    const float* __restrict__ rstd,
    const float* __restrict__ g1, const float* __restrict__ bln1,
    const ushort_t* __restrict__ Qb, const ushort_t* __restrict__ Sb,
    const ushort_t* __restrict__ w1t,    // [96][384] bf16
    const float* __restrict__ b1mlp,
    ushort_t* __restrict__ h4){          // both halves
  __shared__ ushort_t Zs[64][392];       // bf16 Z tile, padded stride
  __shared__ float m1s[384], g1s[384], b1s[384];
  __shared__ float mus[64], rss[64];
  __shared__ float b1m[96];
  const size_t H4S = (size_t)512*196*96;
  int bid = blockIdx.x;
  int sh = bid >= 2048; bid -= sh*2048;
  const float* x = sh ? xs : xq;
  const float* m1_base = mlp1 + (size_t)sh*512*384;
  const float* mu_s = mu + (size_t)sh*100864;
  const float* rstd_s = rstd + (size_t)sh*100864;
  const ushort_t* Qin = sh ? Sb : Qb;
  ushort_t* h4s = h4 + (size_t)sh*H4S;
  int b = bid >> 2, tt0 = (bid & 3)*64;
  int tid = threadIdx.x;
  const float* m1 = m1_base + (size_t)b*384;
  for (int i = tid; i < 384; i += 256){ m1s[i] = m1[i]; g1s[i] = g1[i]; b1s[i] = bln1[i]; }
  if (tid < 96) b1m[tid] = b1mlp[tid];
  if (tid < 64){
    int t = tt0 + tid; int tc = t < 196 ? t : 195;
    mus[tid] = mu_s[b*197 + tc + 1]; rss[tid] = rstd_s[b*197 + tc + 1];
  }
  __syncthreads();
  for (int e = 0; e < 24; ++e){
    int v = e*256 + tid;
    int row = v/96, col4 = v - row*96;
    int t = tt0 + row; int tc = t < 196 ? t : 195;
    float valid = (t < 196) ? 1.f : 0.f;
    float4 xv = *reinterpret_cast<const float4*>(&x[((size_t)b*197 + tc + 1)*384 + col4*4]);
    uint2 qv = *reinterpret_cast<const uint2*>(&Qin[((size_t)b*196 + tc)*384 + col4*4]);
    float muv = mus[row], rsv = rss[row];
    int c = col4*4;
    float z0 = (((xv.x + m1s[c+0]) - muv)*rsv*g1s[c+0] + b1s[c+0]) * bfu(qv.x)      * valid;
    float z1 = (((xv.y + m1s[c+1]) - muv)*rsv*g1s[c+1] + b1s[c+1]) * bfu(qv.x>>16)  * valid;
    float z2 = (((xv.z + m1s[c+2]) - muv)*rsv*g1s[c+2] + b1s[c+2]) * bfu(qv.y)      * valid;
    float z3 = (((xv.w + m1s[c+3]) - muv)*rsv*g1s[c+3] + b1s[c+3]) * bfu(qv.y>>16)  * valid;
    uint2 pk; pk.x = f2b(z0) | (f2b(z1)<<16); pk.y = f2b(z2) | (f2b(z3)<<16);
    *reinterpret_cast<uint2*>(&Zs[row][col4*4]) = pk;
  }
  __syncthreads();
  int w = tid >> 6, lane = tid & 63;
  int tr = tt0 + w*16 + (lane & 15);
  int kg = lane >> 4;
  f32x4 acc0 = {0.f,0.f,0.f,0.f}, acc1 = {0.f,0.f,0.f,0.f}, acc2 = {0.f,0.f,0.f,0.f};
  f32x4 acc3 = {0.f,0.f,0.f,0.f}, acc4 = {0.f,0.f,0.f,0.f}, acc5 = {0.f,0.f,0.f,0.f};
  const ushort_t* arow = w1t + (size_t)(lane & 15)*384 + kg*8;
  const ushort_t* zrow = &Zs[w*16 + (lane & 15)][kg*8];
  for (int kc = 0; kc < 12; ++kc){
    bf16x8 zb = *reinterpret_cast<const bf16x8*>(zrow + kc*32);
    bf16x8 a0 = *reinterpret_cast<const bf16x8*>(arow + kc*32);
    bf16x8 a1 = *reinterpret_cast<const bf16x8*>(arow + kc*32 + 16*384);
    bf16x8 a2 = *reinterpret_cast<const bf16x8*>(arow + kc*32 + 32*384);
    bf16x8 a3 = *reinterpret_cast<const bf16x8*>(arow + kc*32 + 48*384);
    bf16x8 a4 = *reinterpret_cast<const bf16x8*>(arow + kc*32 + 64*384);
    bf16x8 a5 = *reinterpret_cast<const bf16x8*>(arow + kc*32 + 80*384);
    acc0 = __builtin_amdgcn_mfma_f32_16x16x32_bf16(a0, zb, acc0, 0, 0, 0);
    acc1 = __builtin_amdgcn_mfma_f32_16x16x32_bf16(a1, zb, acc1, 0, 0, 0);
    acc2 = __builtin_amdgcn_mfma_f32_16x16x32_bf16(a2, zb, acc2, 0, 0, 0);
    acc3 = __builtin_amdgcn_mfma_f32_16x16x32_bf16(a3, zb, acc3, 0, 0, 0);
    acc4 = __builtin_amdgcn_mfma_f32_16x16x32_bf16(a4, zb, acc4, 0, 0, 0);
    acc5 = __builtin_amdgcn_mfma_f32_16x16x32_bf16(a5, zb, acc5, 0, 0, 0);
  }
  if (tr < 196){
    ushort_t* dst = h4s + ((size_t)b*196 + tr)*96 + kg*4;
    #pragma unroll
    for (int jb = 0; jb < 6; ++jb){
      f32x4 y = (jb==0)?acc0:(jb==1)?acc1:(jb==2)?acc2:(jb==3)?acc3:(jb==4)?acc4:acc5;
      int j0 = jb*16 + kg*4;
      uint2 pk;
      pk.x = f2b(geluf(y[0]+b1m[j0+0])) | (f2b(geluf(y[1]+b1m[j0+1]))<<16);
      pk.y = f2b(geluf(y[2]+b1m[j0+2])) | (f2b(geluf(y[3]+b1m[j0+3]))<<16);
      *reinterpret_cast<uint2*>(dst + jb*16) = pk;
    }
  }
}

// ---------------- H2: fc4 stage B (q+s merged; grid 4096) ----------------
__global__ __launch_bounds__(256) void k_fc4b(
    const ushort_t* __restrict__ h4,
    const ushort_t* __restrict__ w2t,    // [384][96] bf16
    const float* __restrict__ b2, const float* __restrict__ g4,
    const float* __restrict__ bb4,
    const float* __restrict__ dout,
    ushort_t* __restrict__ Qb, ushort_t* __restrict__ Sb){
  __shared__ float b2s[384], g4s[384], b4s[384], cl_s[384];
  const size_t H4S = (size_t)512*196*96;
  int bid = blockIdx.x;
  int sh = bid >= 2048; bid -= sh*2048;
  const ushort_t* h4s = h4 + (size_t)sh*H4S;
  const float* cls_base = dout + 1024 + (size_t)sh*196608;
  ushort_t* Qo = sh ? Sb : Qb;
  int b = bid >> 2, ttile = bid & 3;
  int tid = threadIdx.x, w = tid >> 6, lane = tid & 63;
  const float* cls = cls_base + (size_t)b*384;
  for (int i = tid; i < 384; i += 256){
    b2s[i] = b2[i]; g4s[i] = g4[i]; b4s[i] = bb4[i]; cl_s[i] = cls[i];
  }
  __syncthreads();
  int tr = ttile*64 + w*16 + (lane & 15);
  int trc = tr < 196 ? tr : 195;
  int kg = lane >> 4;
  const ushort_t* hp = h4s + ((size_t)b*196 + trc)*96 + kg*8;
  bf16x8 hb0 = *reinterpret_cast<const bf16x8*>(hp);
  bf16x8 hb1 = *reinterpret_cast<const bf16x8*>(hp + 32);
  bf16x8 hb2 = *reinterpret_cast<const bf16x8*>(hp + 64);
  const ushort_t* ap_base = w2t + (size_t)(lane & 15)*96 + kg*8;
  f32x4 acc[24];
  #pragma unroll
  for (int af = 0; af < 24; ++af){
    const ushort_t* ap = ap_base + (size_t)af*16*96;
    bf16x8 a0 = *reinterpret_cast<const bf16x8*>(ap);
    bf16x8 a1 = *reinterpret_cast<const bf16x8*>(ap + 32);
    bf16x8 a2 = *reinterpret_cast<const bf16x8*>(ap + 64);
    f32x4 z = {0.f,0.f,0.f,0.f};
    z = __builtin_amdgcn_mfma_f32_16x16x32_bf16(a0, hb0, z, 0, 0, 0);
    z = __builtin_amdgcn_mfma_f32_16x16x32_bf16(a1, hb1, z, 0, 0, 0);
    z = __builtin_amdgcn_mfma_f32_16x16x32_bf16(a2, hb2, z, 0, 0, 0);
    acc[af] = z;
  }
  float sum = 0.f, sq = 0.f;
  #pragma unroll
  for (int af = 0; af < 24; ++af){
    int cb = af*16 + kg*4;
    float4 bv = *reinterpret_cast<const float4*>(&b2s[cb]);
    f32x4 y = acc[af];
    y[0] += bv.x; y[1] += bv.y; y[2] += bv.z; y[3] += bv.w;
    acc[af] = y;
    sum += y[0]+y[1]+y[2]+y[3];
    sq  += y[0]*y[0]+y[1]*y[1]+y[2]*y[2]+y[3]*y[3];
  }
  sum += __shfl_xor(sum, 16); sum += __shfl_xor(sum, 32);
  sq  += __shfl_xor(sq, 16);  sq  += __shfl_xor(sq, 32);
  float m4 = sum*(1.0f/384.0f);
  float rs = rsqrtf(sq*(1.0f/384.0f) - m4*m4 + 1e-5f);
  float s2 = 0.f;
  #pragma unroll
  for (int af = 0; af < 24; ++af){
    int cb = af*16 + kg*4;
    float4 gv = *reinterpret_cast<const float4*>(&g4s[cb]);
    float4 bb = *reinterpret_cast<const float4*>(&b4s[cb]);
    float4 cv = *reinterpret_cast<const float4*>(&cl_s[cb]);
    f32x4 y = acc[af];
    y[0] = (y[0]-m4)*rs*gv.x + bb.x + 0.5f*cv.x;
    y[1] = (y[1]-m4)*rs*gv.y + bb.y + 0.5f*cv.y;
    y[2] = (y[2]-m4)*rs*gv.z + bb.z + 0.5f*cv.z;
    y[3] = (y[3]-m4)*rs*gv.w + bb.w + 0.5f*cv.w;
    acc[af] = y;
    s2 += y[0]*y[0]+y[1]*y[1]+y[2]*y[2]+y[3]*y[3];
  }
  s2 += __shfl_xor(s2, 16); s2 += __shfl_xor(s2, 32);
  float inv = 1.0f/fmaxf(sqrtf(s2), 1e-12f);
  float sm = 0.f;
  #pragma unroll
  for (int af = 0; af < 24; ++af){
    f32x4 y = acc[af];
    y[0]*=inv; y[1]*=inv; y[2]*=inv; y[3]*=inv;
    acc[af] = y;
    sm += y[0]+y[1]+y[2]+y[3];
  }
  sm += __shfl_xor(sm, 16); sm += __shfl_xor(sm, 32);
  sm *= (1.0f/384.0f);
  if (tr < 196){
    ushort_t* dst = Qo + ((size_t)b*196 + tr)*384 + kg*4;
    #pragma unroll
    for (int af = 0; af < 24; ++af){
      f32x4 y = acc[af];
      uint2 pk;
      pk.x = f2b(y[0]-sm) | (f2b(y[1]-sm)<<16);
      pk.y = f2b(y[2]-sm) | (f2b(y[3]-sm)<<16);
      *reinterpret_cast<uint2*>(dst + af*16) = pk;
    }
  }
}

// ---------------- I: batched einsum + fused 2x2 pooling (MFMA) ----------------
__global__ __launch_bounds__(256) void k_sim(
    const ushort_t* __restrict__ Q, const ushort_t* __restrict__ S,
    float* __restrict__ P){
  int bid0 = blockIdx.x;
  int bx = (bid0 & 7)*1024 + (bid0 >> 3);   // bijective: consecutive work-b per XCD
  int b = bx >> 4, qt = (bx >> 2) & 3, st = bx & 3;
  int tid = threadIdx.x;
  int w = tid >> 6, lane = tid & 63;
  int wr = w >> 1, wc = w & 1;
  int q0 = qt*64 + wr*32, s0 = st*64 + wc*32;
  int rrow = lane & 15, kg = lane >> 4;
  const ushort_t* Qb_ = Q + (size_t)b*196*384;
  const ushort_t* Sb_ = S + (size_t)b*196*384;
  int qr0 = min(q0 + rrow, 195), qr1 = min(q0 + 16 + rrow, 195);
  int sr0 = min(s0 + rrow, 195), sr1 = min(s0 + 16 + rrow, 195);
  const ushort_t* qp0 = Qb_ + (size_t)qr0*384 + kg*8;
  const ushort_t* qp1 = Qb_ + (size_t)qr1*384 + kg*8;
  const ushort_t* sp0 = Sb_ + (size_t)sr0*384 + kg*8;
  const ushort_t* sp1 = Sb_ + (size_t)sr1*384 + kg*8;
  f32x4 acc00 = {0.f,0.f,0.f,0.f}, acc01 = {0.f,0.f,0.f,0.f};
  f32x4 acc10 = {0.f,0.f,0.f,0.f}, acc11 = {0.f,0.f,0.f,0.f};
  bf16x8 qa0 = *reinterpret_cast<const bf16x8*>(qp0);
  bf16x8 qa1 = *reinterpret_cast<const bf16x8*>(qp1);
  bf16x8 sa0 = *reinterpret_cast<const bf16x8*>(sp0);
  bf16x8 sa1 = *reinterpret_cast<const bf16x8*>(sp1);
  for (int kc = 0; kc < 11; ++kc){
    int koff = (kc+1)*32;
    bf16x8 nq0 = *reinterpret_cast<const bf16x8*>(qp0 + koff);
    bf16x8 nq1 = *reinterpret_cast<const bf16x8*>(qp1 + koff);
    bf16x8 ns0 = *reinterpret_cast<const bf16x8*>(sp0 + koff);
    bf16x8 ns1 = *reinterpret_cast<const bf16x8*>(sp1 + koff);
    acc00 = __builtin_amdgcn_mfma_f32_16x16x32_bf16(qa0, sa0, acc00, 0, 0, 0);
    acc01 = __builtin_amdgcn_mfma_f32_16x16x32_bf16(qa0, sa1, acc01, 0, 0, 0);
    acc10 = __builtin_amdgcn_mfma_f32_16x16x32_bf16(qa1, sa0, acc10, 0, 0, 0);
    acc11 = __builtin_amdgcn_mfma_f32_16x16x32_bf16(qa1, sa1, acc11, 0, 0, 0);
    qa0 = nq0; qa1 = nq1; sa0 = ns0; sa1 = ns1;
  }
  acc00 = __builtin_amdgcn_mfma_f32_16x16x32_bf16(qa0, sa0, acc00, 0, 0, 0);
  acc01 = __builtin_amdgcn_mfma_f32_16x16x32_bf16(qa0, sa1, acc01, 0, 0, 0);
  acc10 = __builtin_amdgcn_mfma_f32_16x16x32_bf16(qa1, sa0, acc10, 0, 0, 0);
  acc11 = __builtin_amdgcn_mfma_f32_16x16x32_bf16(qa1, sa1, acc11, 0, 0, 0);
  int c = lane & 15, g = lane >> 4;
  float* Pb = P + (size_t)b*98*98;
  #pragma unroll
  for (int i = 0; i < 2; ++i){
    #pragma unroll
    for (int j = 0; j < 2; ++j){
      f32x4 v = (i==0) ? (j==0 ? acc00 : acc01) : (j==0 ? acc10 : acc11);
      float p0 = v[0] + v[1];   // rows 4g, 4g+1
      float p1 = v[2] + v[3];   // rows 4g+2, 4g+3
      float t0 = p0 + __shfl_xor(p0, 1);
      float t1 = p1 + __shfl_xor(p1, 1);
      if (!(c & 1)){
        int qp = (q0 + 16*i + 4*g) >> 1;
        int sp = (s0 + 16*j + c) >> 1;
        if (sp < 98){
          if (qp     < 98) Pb[(size_t)(qp    )*98 + sp] = 0.25f*t0;
          if (qp + 1 < 98) Pb[(size_t)(qp + 1)*98 + sp] = 0.25f*t1;
        }
      }
    }
  }
}

// ---------------- J1: fc2 split-K GEMM  Cpart[ks] = P2-chunk @ w1-chunk ----------------
__global__ __launch_bounds__(256) void k_fc2a(
    const float* __restrict__ P, const float* __restrict__ w1,
    float* __restrict__ Cpart){
  __shared__ float p2[8][688];
  int bx = blockIdx.x;
  int mb = bx & 63, ks = bx >> 6;      // 14 k-splits of 686 (14*686 = 9604)
  int b0 = mb*8, k0 = ks*686;
  int tid = threadIdx.x;
  for (int idx = tid; idx < 8*686; idx += 256){
    int r = idx / 686, i = idx - r*686;
    float v = P[(size_t)(b0+r)*9604 + k0 + i];
    p2[r][i] = v*v;
  }
  __syncthreads();
  float acc[8];
  #pragma unroll
  for (int r=0;r<8;++r) acc[r]=0.f;
  for (int ii=0; ii<686; ++ii){
    float w = w1[(size_t)(k0+ii)*256 + tid];
    #pragma unroll
    for (int r=0;r<8;++r) acc[r] += p2[r][ii]*w;
  }
  #pragma unroll
  for (int r=0;r<8;++r) Cpart[((size_t)ks*512 + b0 + r)*256 + tid] = acc[r];
}

// ---------------- J2: fc2 reduce + gelu + w2 dot ----------------
__global__ __launch_bounds__(256) void k_fc2b(
    const float* __restrict__ Cpart, const float* __restrict__ b1,
    const float* __restrict__ w2, const float* __restrict__ b2,
    float* __restrict__ outp){
  __shared__ float red[4];
  int b = blockIdx.x, tid = threadIdx.x;
  float s = 0.f;
  for (int ks = 0; ks < 14; ++ks) s += Cpart[((size_t)ks*512 + b)*256 + tid];
  float h = geluf(s + b1[tid]) * w2[tid];
  #pragma unroll
  for (int o=32;o;o>>=1) h += __shfl_down(h,o);
  int w = tid >> 6, lane = tid & 63;
  if (lane==0) red[w] = h;
  __syncthreads();
  if (tid==0) outp[b] = red[0]+red[1]+red[2]+red[3] + b2[0];
}

// ---------------- launch ----------------
extern "C" void kernel_launch(void* const* d_in, const int* in_sizes, int n_in,
                              void* d_out, int out_size, void* d_ws, size_t ws_size,
                              hipStream_t stream){
  const float* fq  = (const float*)d_in[0];
  const float* fs  = (const float*)d_in[1];
  const float* fqs = (const float*)d_in[2];
  const float* fss = (const float*)d_in[3];
  const float* fc1_w1 = (const float*)d_in[4];
  const float* fc1_b1 = (const float*)d_in[5];
  const float* fc1_w2 = (const float*)d_in[6];
  const float* fc1_b2 = (const float*)d_in[7];
  const float* ln1_g = (const float*)d_in[8];
  const float* ln1_b = (const float*)d_in[9];
  const float* fc3_w1 = (const float*)d_in[10];
  const float* fc3_b1 = (const float*)d_in[11];
  const float* fc3_w2 = (const float*)d_in[12];
  const float* fc3_b2 = (const float*)d_in[13];
  const float* ln3_g = (const float*)d_in[14];
  const float* ln3_b = (const float*)d_in[15];
  const float* fc4_w1 = (const float*)d_in[16];
  const float* fc4_b1 = (const float*)d_in[17];
  const float* fc4_w2 = (const float*)d_in[18];
  const float* fc4_b2 = (const float*)d_in[19];
  const float* ln4_g = (const float*)d_in[20];
  const float* ln4_b = (const float*)d_in[21];
  const float* fc2_w1 = (const float*)d_in[22];
  const float* fc2_b1 = (const float*)d_in[23];
  const float* fc2_w2 = (const float*)d_in[24];
  const float* fc2_b2 = (const float*)d_in[25];
  const float* cs_w1 = (const float*)d_in[26];
  const float* cs_b1 = (const float*)d_in[27];
  const float* cs_w2 = (const float*)d_in[28];
  const float* cs_b2 = (const float*)d_in[29];
  float* out = (float*)d_out;
  char* ws = (char*)d_ws;
  // ws layout (bytes):
  //   w2t  bf16 @0          (73,728)      [fc4 w2^T]
  //   w1t  bf16 @73728      (73,728)      [fc4 w1^T]
  //   w1t3 bf16 @147456     (57,344)      [fc3 w1^T, t-pad 224]
  //   w2t3 bf16 @204800     (53,248)      [fc3 w2^T, t'-pad 208]
  //   mlp1  f32 @3145728    (3,145,728)
  //   mu    f32 @6291456    (1,613,824)
  //   rstd  f32 @7905280    (1,613,824)
  //   h4    bf16 @9519104   (38,535,168)  [then P f32 + Cpart overlay]
  //   P     f32 @9519104    (19,668,992)  [overlays h4 (dead after fc4b)]
  //   Cpart f32 @29188096   (7,340,032)
  //   Qb    bf16 @59850752  (77,070,336)
  //   Sb    bf16 @136921088 (77,070,336)
  //   total 213,991,424 B
  ushort_t* w2t  = (ushort_t*)(ws + 0);
  ushort_t* w1t  = (ushort_t*)(ws + 73728);
  ushort_t* w1t3 = (ushort_t*)(ws + 147456);
  ushort_t* w2t3 = (ushort_t*)(ws + 204800);
  float* mlp1   = (float*)(ws + 3145728);
  float* mu     = (float*)(ws + 6291456);
  float* rstd   = (float*)(ws + 7905280);
  ushort_t* h4  = (ushort_t*)(ws + 9519104);
  float* P      = (float*)(ws + 9519104);     // overlays h4 (dead after fc4b)
  float* Cpart  = (float*)(ws + 29188096);    // after P, before Qb
  ushort_t* Qb  = (ushort_t*)(ws + 59850752);
  ushort_t* Sb  = (ushort_t*)(ws + 136921088);

  k_wt<<<504, 256, 0, stream>>>(fc4_w1, fc4_w2, fc3_w1, fc3_w2,
                                w1t, w2t, w1t3, w2t3);
  // fused mean + fc1 + LN-stats (single pass over all four inputs; 12 waves/CU)
  k_ms<<<2048, 768, 0, stream>>>(fq, fs, fqs, fss,
                                 fc1_w1, fc1_b1, fc1_w2, fc1_b2,
                                 mlp1, mu, rstd);
  k_class<<<1024, 384, 0, stream>>>(fq, fs, mlp1, mu, rstd, ln1_g, ln1_b, out);
  k_cosine<<<512, 384, 0, stream>>>(cs_w1, cs_b1, cs_w2, cs_b2, out);
  // fc3 fused MFMA, q+s merged (one launch, 6144 blocks)
  k_fc3<<<6144, 256, 0, stream>>>(fqs, fss, mlp1, mu, rstd,
                                  ln1_g, ln1_b, w1t3, fc3_b1, w2t3, fc3_b2,
                                  ln3_g, ln3_b, Qb, Sb);
  // fc4 stage A, q+s merged (one launch, 4096 blocks)
  k_fc4a<<<4096, 256, 0, stream>>>(fq, fs, mlp1, mu, rstd, ln1_g, ln1_b,
                                   Qb, Sb, w1t, fc4_b1, h4);
  // fc4 stage B, q+s merged (Qb/Sb overwritten in place after their last read)
  k_fc4b<<<4096, 256, 0, stream>>>(h4, w2t, fc4_b2, ln4_g, ln4_b, out, Qb, Sb);
  k_sim<<<8192, 256, 0, stream>>>(Qb, Sb, P);
  // fc2 head: split-K GEMM (896 blocks) + tiny reduce
  k_fc2a<<<896, 256, 0, stream>>>(P, fc2_w1, Cpart);
  k_fc2b<<<512, 256, 0, stream>>>(Cpart, fc2_b1, fc2_w2, fc2_b2, out);
}